// Round 1
// baseline (3008.501 us; speedup 1.0000x reference)
//
#include <hip/hip_runtime.h>

typedef short short8 __attribute__((ext_vector_type(8)));
typedef float f32x4 __attribute__((ext_vector_type(4)));

__device__ __forceinline__ unsigned short f2bf(float f) {
  union { float f; unsigned u; } a; a.f = f;
  unsigned r = a.u + 0x7fffu + ((a.u >> 16) & 1u);
  return (unsigned short)(r >> 16);
}

// ---------------- tap offset table: off[k] = ci*3136 + ky*56 + kx ----------------
__global__ void offtab_k(unsigned* __restrict__ off_tab) {
  const int k = blockIdx.x * 256 + threadIdx.x;  // 81*256 = 20736 exact
  const int ci = k / 81, rr = k % 81;
  const int ky = rr / 9, kx = rr % 9;
  off_tab[k] = (unsigned)(ci * 3136 + ky * 56 + kx);
}

// ---------------- prim_w fp32 -> bf16 tiled [kb][co][8] ----------------
__global__ __launch_bounds__(256) void wconv_k(const float* __restrict__ pw,
                                               unsigned short* __restrict__ wbf) {
  const int kb = blockIdx.x, co = threadIdx.x;  // 2592 blocks
  const float4* src = (const float4*)(pw + (long)co * 20736 + kb * 8);
  const float4 a = src[0], b = src[1];
  union { unsigned short s[8]; short8 v; } o;
  o.s[0] = f2bf(a.x); o.s[1] = f2bf(a.y); o.s[2] = f2bf(a.z); o.s[3] = f2bf(a.w);
  o.s[4] = f2bf(b.x); o.s[5] = f2bf(b.y); o.s[6] = f2bf(b.z); o.s[7] = f2bf(b.w);
  *reinterpret_cast<short8*>(&wbf[((long)kb * 256 + co) * 8]) = o.v;
}

// ---------------- conv1: [8,3,64,64] -> bf16 h [8,256,56,56], relu ----------------
__global__ __launch_bounds__(256) void conv1_k(const float* __restrict__ x,
                                               const float* __restrict__ w,
                                               const float* __restrict__ bias,
                                               unsigned short* __restrict__ h_bf) {
  __shared__ float xl[12288];
  __shared__ float wl[244];
  const int blk = blockIdx.x;          // 2048 = 8b * 256co
  const int b = blk >> 8, co = blk & 255;
  const int t = threadIdx.x;
  const float4* xb = (const float4*)(x + b * 12288);
  float4* xl4 = (float4*)xl;
  for (int r = t; r < 3072; r += 256) xl4[r] = xb[r];
  for (int r = t; r < 243; r += 256) wl[r] = w[co * 243 + r];
  __syncthreads();
  if (t >= 224) return;
  const int ox = t % 56, oy0 = (t / 56) * 14;
  float acc[14];
#pragma unroll
  for (int j = 0; j < 14; ++j) acc[j] = 0.f;
  for (int ci = 0; ci < 3; ++ci)
    for (int kx = 0; kx < 9; ++kx) {
      const int base = ci * 4096 + oy0 * 64 + ox + kx;
      float win[22];
#pragma unroll
      for (int q = 0; q < 22; ++q) win[q] = xl[base + q * 64];
#pragma unroll
      for (int ky = 0; ky < 9; ++ky) {
        const float wv = wl[ci * 81 + ky * 9 + kx];
#pragma unroll
        for (int j = 0; j < 14; ++j) acc[j] = fmaf(wv, win[j + ky], acc[j]);
      }
    }
  const float bv = bias[co];
  unsigned short* hp = h_bf + (((long)b * 256 + co) * 56 + oy0) * 56 + ox;
#pragma unroll
  for (int j = 0; j < 14; ++j) {
    float v = acc[j] + bv;
    v = v > 0.f ? v : 0.f;
    hp[j * 56] = f2bf(v);
  }
}

// ---------------- prim conv implicit GEMM: C[m=4608][co=256], K=20736 ----------------
// grid (72 mtile, 4 ntile, 4 ksplit), 256 thr. mfma 16x16x32 bf16, 64x64 tile.
__global__ __launch_bounds__(256) void prim_gemm(const unsigned short* __restrict__ h_bf,
                                                 const unsigned short* __restrict__ wbf,
                                                 const unsigned* __restrict__ off_tab,
                                                 float* __restrict__ C_part) {
  __shared__ unsigned short A_l[64 * 40];
  __shared__ unsigned short B_l[64 * 40];
  const int t = threadIdx.x;
  const int lane = t & 63, kkg = t >> 6;  // kkg == wave id
  const int mt = blockIdx.x, nt = blockIdx.y, kz = blockIdx.z;
  const int m = mt * 64 + lane;
  const int b = m / 576, yx = m % 576;
  const int oy = yx / 24, ox = yx % 24;
  const long base_p = (long)b * 802816 + oy * 112 + ox * 2;  // iy=2oy, ix=2ox
  const int cog = nt * 64 + lane;
  const int k0 = kz * 5184;
  const int wm = kkg & 1, wn = kkg >> 1;
  const int fr = lane & 15, fg = lane >> 4;
  f32x4 acc[2][2];
#pragma unroll
  for (int a = 0; a < 2; ++a)
#pragma unroll
    for (int c = 0; c < 2; ++c)
#pragma unroll
      for (int e = 0; e < 4; ++e) acc[a][c][e] = 0.f;
  for (int kt = 0; kt < 162; ++kt) {
    const int k = k0 + kt * 32;
    union { unsigned short s[8]; short8 v; } au;
#pragma unroll
    for (int j = 0; j < 8; ++j) {
      const unsigned o = off_tab[k + kkg * 8 + j];  // wave-uniform (broadcast)
      au.s[j] = h_bf[base_p + o];
    }
    *reinterpret_cast<short8*>(&A_l[lane * 40 + kkg * 8]) = au.v;
    const short8 bvv = *reinterpret_cast<const short8*>(
        &wbf[(((long)(k >> 3) + kkg) * 256 + cog) * 8]);
    *reinterpret_cast<short8*>(&B_l[lane * 40 + kkg * 8]) = bvv;
    __syncthreads();
    const short8 a0 = *reinterpret_cast<const short8*>(&A_l[(wm * 32 + fr) * 40 + fg * 8]);
    const short8 a1 = *reinterpret_cast<const short8*>(&A_l[(wm * 32 + 16 + fr) * 40 + fg * 8]);
    const short8 b0 = *reinterpret_cast<const short8*>(&B_l[(wn * 32 + fr) * 40 + fg * 8]);
    const short8 b1 = *reinterpret_cast<const short8*>(&B_l[(wn * 32 + 16 + fr) * 40 + fg * 8]);
    acc[0][0] = __builtin_amdgcn_mfma_f32_16x16x32_bf16(a0, b0, acc[0][0], 0, 0, 0);
    acc[0][1] = __builtin_amdgcn_mfma_f32_16x16x32_bf16(a0, b1, acc[0][1], 0, 0, 0);
    acc[1][0] = __builtin_amdgcn_mfma_f32_16x16x32_bf16(a1, b0, acc[1][0], 0, 0, 0);
    acc[1][1] = __builtin_amdgcn_mfma_f32_16x16x32_bf16(a1, b1, acc[1][1], 0, 0, 0);
    __syncthreads();
  }
#pragma unroll
  for (int i2 = 0; i2 < 2; ++i2)
#pragma unroll
    for (int j2 = 0; j2 < 2; ++j2)
#pragma unroll
      for (int e = 0; e < 4; ++e) {
        const int row = mt * 64 + wm * 32 + i2 * 16 + fg * 4 + e;  // C row = (l>>4)*4+reg
        const int col = nt * 64 + wn * 32 + j2 * 16 + fr;          // C col = lane&15
        C_part[((long)kz * 4608 + row) * 256 + col] = acc[i2][j2][e];
      }
}

// ---------------- combine K-split partials + bias + squash -> u [8,18432,8] ----------------
__global__ __launch_bounds__(256) void combine_k(const float* __restrict__ C_part,
                                                 const float* __restrict__ prim_b,
                                                 float* __restrict__ u) {
  const int cap = blockIdx.x * 256 + threadIdx.x;  // 576*256 = 147456 exact
  const int b = cap / 18432, r = cap % 18432;
  const int g = r / 576, yx = r % 576;
  const long m = (long)b * 576 + yx;
  float pv[8];
#pragma unroll
  for (int e = 0; e < 8; ++e) pv[e] = prim_b[g * 8 + e];
#pragma unroll
  for (int kz = 0; kz < 4; ++kz) {
    const float4* cp = (const float4*)(C_part + ((long)kz * 4608 + m) * 256 + g * 8);
    const float4 f0 = cp[0], f1 = cp[1];
    pv[0] += f0.x; pv[1] += f0.y; pv[2] += f0.z; pv[3] += f0.w;
    pv[4] += f1.x; pv[5] += f1.y; pv[6] += f1.z; pv[7] += f1.w;
  }
  float sn = 0.f;
#pragma unroll
  for (int e = 0; e < 8; ++e) sn += pv[e] * pv[e];
  const float f = sn / (1.f + sn) / (sqrtf(sn) + 1e-8f);
  float4 o0, o1;
  o0.x = pv[0] * f; o0.y = pv[1] * f; o0.z = pv[2] * f; o0.w = pv[3] * f;
  o1.x = pv[4] * f; o1.y = pv[5] * f; o1.z = pv[6] * f; o1.w = pv[7] * f;
  float4* up = (float4*)(u + (long)cap * 8);
  up[0] = o0; up[1] = o1;
}

// ---------------- routing pass: logits = dot(u_hat, vsum); softmax_n; S += sc*u_hat ----
// thread t: b = t>>5, d = (t>>1)&15, nh = t&1 ; each thread owns 25 classes.
__global__ __launch_bounds__(256) void route_pass(const float* __restrict__ W,
                                                  const float* __restrict__ u,
                                                  const float* __restrict__ vsum,
                                                  float* __restrict__ S_part) {
  const int t = threadIdx.x;
  const int b = t >> 5, d = (t >> 1) & 15, nh = t & 1;
  const int nbase = nh * 25;
  float vs[25], Sa[25], uh[25], lg[25];
#pragma unroll
  for (int q = 0; q < 25; ++q) {
    vs[q] = vsum[(b * 50 + nbase + q) * 16 + d];
    Sa[q] = 0.f;
  }
  const int bi = blockIdx.x;
  for (int ii = 0; ii < 72; ++ii) {
    const int i = ii * 256 + bi;
    const float4* up = (const float4*)(u + ((long)b * 18432 + i) * 8);
    const float4 u0 = up[0], u1 = up[1];
    const float* Wbase = W + (long)i * 128 + d * 8;
#pragma unroll
    for (int q = 0; q < 25; ++q) {
      const float4* wp = (const float4*)(Wbase + (long)(nbase + q) * 2359296);
      const float4 w0 = wp[0], w1 = wp[1];
      const float s = w0.x * u0.x + w0.y * u0.y + w0.z * u0.z + w0.w * u0.w +
                      w1.x * u1.x + w1.y * u1.y + w1.z * u1.z + w1.w * u1.w;
      uh[q] = s;
      lg[q] = s * vs[q];
    }
#pragma unroll
    for (int q = 0; q < 25; ++q) {  // reduce over d lanes (bits 1..4)
      float v = lg[q];
      v += __shfl_xor(v, 2);
      v += __shfl_xor(v, 4);
      v += __shfl_xor(v, 8);
      v += __shfl_xor(v, 16);
      lg[q] = v;
    }
    float mx = lg[0];
#pragma unroll
    for (int q = 1; q < 25; ++q) mx = fmaxf(mx, lg[q]);
    mx = fmaxf(mx, __shfl_xor(mx, 1));  // combine n-halves
    float sm = 0.f;
#pragma unroll
    for (int q = 0; q < 25; ++q) {
      const float e = __expf(lg[q] - mx);
      lg[q] = e;
      sm += e;
    }
    sm += __shfl_xor(sm, 1);
    const float inv = 1.f / sm;
#pragma unroll
    for (int q = 0; q < 25; ++q) Sa[q] = fmaf(lg[q] * inv, uh[q], Sa[q]);
  }
#pragma unroll
  for (int q = 0; q < 25; ++q)
    S_part[(((long)bi * 8 + b) * 50 + nbase + q) * 16 + d] = Sa[q];
}

// ---------------- reduce partials -> v = squash(S); vsum += v (pass<3) or v3 = v ------
__global__ __launch_bounds__(256) void route_reduce(const float* __restrict__ S_part,
                                                    float* __restrict__ vsum,
                                                    float* __restrict__ v3,
                                                    const int pass) {
  const int b = blockIdx.x, t = threadIdx.x;
  const int nl = t >> 4, d = t & 15;
  for (int c = 0; c < 4; ++c) {
    const int n = c * 16 + nl;
    float s = 0.f;
    if (n < 50) {
      const float* p = S_part + ((long)b * 50 + n) * 16 + d;
      for (int k = 0; k < 256; ++k) s += p[(long)k * 6400];
    }
    float sq = s * s;  // reduce |S|^2 over d lanes (bits 0..3)
    sq += __shfl_xor(sq, 1);
    sq += __shfl_xor(sq, 2);
    sq += __shfl_xor(sq, 4);
    sq += __shfl_xor(sq, 8);
    if (n < 50) {
      const float f = sq / (1.f + sq) / (sqrtf(sq) + 1e-8f);
      const float v = s * f;
      const int o = (b * 50 + n) * 16 + d;
      if (pass < 3) vsum[o] += v;
      else v3[o] = v;
    }
  }
}

// ---------------- preds, argmax, select masked capsule ----------------
__global__ __launch_bounds__(512) void head_k(const float* __restrict__ v3,
                                              float* __restrict__ out,
                                              float* __restrict__ selv,
                                              int* __restrict__ idxs) {
  __shared__ float pl[400];
  const int t = threadIdx.x;
  if (t < 400) {
    const float4* vp = (const float4*)(v3 + t * 16);
    const float4 a = vp[0], b = vp[1], c = vp[2], d = vp[3];
    const float s = a.x * a.x + a.y * a.y + a.z * a.z + a.w * a.w +
                    b.x * b.x + b.y * b.y + b.z * b.z + b.w * b.w +
                    c.x * c.x + c.y * c.y + c.z * c.z + c.w * c.w +
                    d.x * d.x + d.y * d.y + d.z * d.z + d.w * d.w;
    const float p = sqrtf(s);
    out[t] = p;   // preds, flat [8,50]
    pl[t] = p;
  }
  __syncthreads();
  if (t < 8) {
    float best = -1e30f;
    int bi = 0;
    for (int n = 0; n < 50; ++n) {
      const float p = pl[t * 50 + n];
      if (p > best) { best = p; bi = n; }  // first max, matches argmax
    }
    idxs[t] = bi;
    for (int k = 0; k < 16; ++k) selv[t * 16 + k] = v3[(t * 50 + bi) * 16 + k];
  }
}

// ---------------- decoder ----------------
__global__ __launch_bounds__(512) void d1_k(const float* __restrict__ selv,
                                            const int* __restrict__ idxs,
                                            const float* __restrict__ d1w,
                                            const float* __restrict__ d1b,
                                            float* __restrict__ r1) {
  const int b = blockIdx.x, j = threadIdx.x;
  const int idx = idxs[b];
  const float* wr = d1w + j * 800 + idx * 16;
  float acc = d1b[j];
#pragma unroll
  for (int k = 0; k < 16; ++k) acc = fmaf(selv[b * 16 + k], wr[k], acc);
  r1[b * 512 + j] = acc > 0.f ? acc : 0.f;
}

__global__ __launch_bounds__(256) void d2_k(const float* __restrict__ r1,
                                            const float* __restrict__ d2w,
                                            const float* __restrict__ d2b,
                                            float* __restrict__ r2) {
  __shared__ float rl[512];
  const int b = blockIdx.y;
  const int j = blockIdx.x * 256 + threadIdx.x;
  for (int r = threadIdx.x; r < 512; r += 256) rl[r] = r1[b * 512 + r];
  __syncthreads();
  const float4* wr = (const float4*)(d2w + (long)j * 512);
  float acc = d2b[j];
  for (int k4 = 0; k4 < 128; ++k4) {
    const float4 w = wr[k4];
    acc += w.x * rl[k4 * 4] + w.y * rl[k4 * 4 + 1] + w.z * rl[k4 * 4 + 2] + w.w * rl[k4 * 4 + 3];
  }
  r2[b * 1024 + j] = acc > 0.f ? acc : 0.f;
}

__global__ __launch_bounds__(256) void d3_k(const float* __restrict__ r2,
                                            const float* __restrict__ d3w,
                                            const float* __restrict__ d3b,
                                            float* __restrict__ out) {
  __shared__ float rl[8192];
  const int j = blockIdx.x * 256 + threadIdx.x;
  float4* rl4 = (float4*)rl;
  for (int r = threadIdx.x; r < 2048; r += 256) rl4[r] = ((const float4*)r2)[r];
  __syncthreads();
  float acc[8];
  const float bv = d3b[j];
#pragma unroll
  for (int b = 0; b < 8; ++b) acc[b] = bv;
  const float4* wr = (const float4*)d3w + (long)j * 256;
  for (int k4 = 0; k4 < 256; ++k4) {
    const float4 w = wr[k4];
#pragma unroll
    for (int b = 0; b < 8; ++b) {
      const int o = b * 1024 + k4 * 4;
      acc[b] += w.x * rl[o] + w.y * rl[o + 1] + w.z * rl[o + 2] + w.w * rl[o + 3];
    }
  }
#pragma unroll
  for (int b = 0; b < 8; ++b)
    out[400 + b * 12288 + j] = 1.f / (1.f + __expf(-acc[b]));
}

extern "C" void kernel_launch(void* const* d_in, const int* in_sizes, int n_in,
                              void* d_out, int out_size, void* d_ws, size_t ws_size,
                              hipStream_t stream) {
  const float* x   = (const float*)d_in[0];
  const float* c1w = (const float*)d_in[1];
  const float* c1b = (const float*)d_in[2];
  const float* pw  = (const float*)d_in[3];
  const float* pb  = (const float*)d_in[4];
  const float* W   = (const float*)d_in[5];
  const float* d1w = (const float*)d_in[6];
  const float* d1b = (const float*)d_in[7];
  const float* d2w = (const float*)d_in[8];
  const float* d2b = (const float*)d_in[9];
  const float* d3w = (const float*)d_in[10];
  const float* d3b = (const float*)d_in[11];
  float* out = (float*)d_out;

  char* wsb = (char*)d_ws;
  size_t off = 0;
  auto alloc = [&](size_t bytes) -> char* {
    char* p = wsb + off;
    off += (bytes + 255) & ~(size_t)255;
    return p;
  };
  unsigned short* h_bf   = (unsigned short*)alloc(12845056);  // bf16 h
  unsigned short* wbf    = (unsigned short*)alloc(10616832);  // bf16 tiled prim_w
  unsigned*       offt   = (unsigned*)alloc(82944);
  float*          C_part = (float*)alloc(18874368);           // 4 K-split partials
  float*          u      = (float*)alloc(4718592);            // squashed caps
  float*          S_part = (float*)alloc(6553600);            // 256 routing partials
  float*          vsum   = (float*)alloc(25600);
  float*          v3     = (float*)alloc(25600);
  float*          selv   = (float*)alloc(512);
  int*            idxs   = (int*)alloc(64);
  float*          r1     = (float*)alloc(16384);
  float*          r2     = (float*)alloc(32768);
  if (off > ws_size) return;  // fail loudly (outputs stay poisoned)

  offtab_k<<<81, 256, 0, stream>>>(offt);
  wconv_k<<<2592, 256, 0, stream>>>(pw, wbf);
  conv1_k<<<2048, 256, 0, stream>>>(x, c1w, c1b, h_bf);
  prim_gemm<<<dim3(72, 4, 4), 256, 0, stream>>>(h_bf, wbf, offt, C_part);
  combine_k<<<576, 256, 0, stream>>>(C_part, pb, u);
  hipMemsetAsync(vsum, 0, 25600, stream);
  for (int pass = 1; pass <= 3; ++pass) {
    route_pass<<<256, 256, 0, stream>>>(W, u, vsum, S_part);
    route_reduce<<<8, 256, 0, stream>>>(S_part, vsum, v3, pass);
  }
  head_k<<<1, 512, 0, stream>>>(v3, out, selv, idxs);
  d1_k<<<8, 512, 0, stream>>>(selv, idxs, d1w, d1b, r1);
  d2_k<<<dim3(4, 8), 256, 0, stream>>>(r1, d2w, d2b, r2);
  d3_k<<<48, 256, 0, stream>>>(r2, d3w, d3b, out);
}

// Round 2
// 1547.152 us; speedup vs baseline: 1.9445x; 1.9445x over previous
//
#include <hip/hip_runtime.h>

typedef short short8 __attribute__((ext_vector_type(8)));
typedef float f32x4 __attribute__((ext_vector_type(4)));

__device__ __forceinline__ unsigned short f2bf(float f) {
  union { float f; unsigned u; } a; a.f = f;
  unsigned r = a.u + 0x7fffu + ((a.u >> 16) & 1u);
  return (unsigned short)(r >> 16);
}

// ---------------- tap offset table: off[k] = ci*3136 + ky*56 + kx ----------------
__global__ void offtab_k(unsigned* __restrict__ off_tab) {
  const int k = blockIdx.x * 256 + threadIdx.x;  // 81*256 = 20736 exact
  const int ci = k / 81, rr = k % 81;
  const int ky = rr / 9, kx = rr % 9;
  off_tab[k] = (unsigned)(ci * 3136 + ky * 56 + kx);
}

// ---------------- prim_w fp32 -> bf16 tiled [kb][co][8] ----------------
__global__ __launch_bounds__(256) void wconv_k(const float* __restrict__ pw,
                                               unsigned short* __restrict__ wbf) {
  const int kb = blockIdx.x, co = threadIdx.x;  // 2592 blocks
  const float4* src = (const float4*)(pw + (long)co * 20736 + kb * 8);
  const float4 a = src[0], b = src[1];
  union { unsigned short s[8]; short8 v; } o;
  o.s[0] = f2bf(a.x); o.s[1] = f2bf(a.y); o.s[2] = f2bf(a.z); o.s[3] = f2bf(a.w);
  o.s[4] = f2bf(b.x); o.s[5] = f2bf(b.y); o.s[6] = f2bf(b.z); o.s[7] = f2bf(b.w);
  *reinterpret_cast<short8*>(&wbf[((long)kb * 256 + co) * 8]) = o.v;
}

// ---------------- conv1: [8,3,64,64] -> bf16 h [8,256,56,56], relu ----------------
__global__ __launch_bounds__(256) void conv1_k(const float* __restrict__ x,
                                               const float* __restrict__ w,
                                               const float* __restrict__ bias,
                                               unsigned short* __restrict__ h_bf) {
  __shared__ float xl[12288];
  __shared__ float wl[244];
  const int blk = blockIdx.x;          // 2048 = 8b * 256co
  const int b = blk >> 8, co = blk & 255;
  const int t = threadIdx.x;
  const float4* xb = (const float4*)(x + b * 12288);
  float4* xl4 = (float4*)xl;
  for (int r = t; r < 3072; r += 256) xl4[r] = xb[r];
  for (int r = t; r < 243; r += 256) wl[r] = w[co * 243 + r];
  __syncthreads();
  if (t >= 224) return;
  const int ox = t % 56, oy0 = (t / 56) * 14;
  float acc[14];
#pragma unroll
  for (int j = 0; j < 14; ++j) acc[j] = 0.f;
  for (int ci = 0; ci < 3; ++ci)
    for (int kx = 0; kx < 9; ++kx) {
      const int base = ci * 4096 + oy0 * 64 + ox + kx;
      float win[22];
#pragma unroll
      for (int q = 0; q < 22; ++q) win[q] = xl[base + q * 64];
#pragma unroll
      for (int ky = 0; ky < 9; ++ky) {
        const float wv = wl[ci * 81 + ky * 9 + kx];
#pragma unroll
        for (int j = 0; j < 14; ++j) acc[j] = fmaf(wv, win[j + ky], acc[j]);
      }
    }
  const float bv = bias[co];
  unsigned short* hp = h_bf + (((long)b * 256 + co) * 56 + oy0) * 56 + ox;
#pragma unroll
  for (int j = 0; j < 14; ++j) {
    float v = acc[j] + bv;
    v = v > 0.f ? v : 0.f;
    hp[j * 56] = f2bf(v);
  }
}

// ---------------- prim conv implicit GEMM: C[m=4608][co=256], K=20736 ----------------
// grid (72 mtile, 4 ntile, 4 ksplit), 256 thr. mfma 16x16x32 bf16, 64x64 tile.
__global__ __launch_bounds__(256) void prim_gemm(const unsigned short* __restrict__ h_bf,
                                                 const unsigned short* __restrict__ wbf,
                                                 const unsigned* __restrict__ off_tab,
                                                 float* __restrict__ C_part) {
  __shared__ unsigned short A_l[64 * 40];
  __shared__ unsigned short B_l[64 * 40];
  const int t = threadIdx.x;
  const int lane = t & 63, kkg = t >> 6;  // kkg == wave id
  const int mt = blockIdx.x, nt = blockIdx.y, kz = blockIdx.z;
  const int m = mt * 64 + lane;
  const int b = m / 576, yx = m % 576;
  const int oy = yx / 24, ox = yx % 24;
  const long base_p = (long)b * 802816 + oy * 112 + ox * 2;  // iy=2oy, ix=2ox
  const int cog = nt * 64 + lane;
  const int k0 = kz * 5184;
  const int wm = kkg & 1, wn = kkg >> 1;
  const int fr = lane & 15, fg = lane >> 4;
  f32x4 acc[2][2];
#pragma unroll
  for (int a = 0; a < 2; ++a)
#pragma unroll
    for (int c = 0; c < 2; ++c)
#pragma unroll
      for (int e = 0; e < 4; ++e) acc[a][c][e] = 0.f;
  for (int kt = 0; kt < 162; ++kt) {
    const int k = k0 + kt * 32;
    union { unsigned short s[8]; short8 v; } au;
#pragma unroll
    for (int j = 0; j < 8; ++j) {
      const unsigned o = off_tab[k + kkg * 8 + j];  // wave-uniform (broadcast)
      au.s[j] = h_bf[base_p + o];
    }
    *reinterpret_cast<short8*>(&A_l[lane * 40 + kkg * 8]) = au.v;
    const short8 bvv = *reinterpret_cast<const short8*>(
        &wbf[(((long)(k >> 3) + kkg) * 256 + cog) * 8]);
    *reinterpret_cast<short8*>(&B_l[lane * 40 + kkg * 8]) = bvv;
    __syncthreads();
    const short8 a0 = *reinterpret_cast<const short8*>(&A_l[(wm * 32 + fr) * 40 + fg * 8]);
    const short8 a1 = *reinterpret_cast<const short8*>(&A_l[(wm * 32 + 16 + fr) * 40 + fg * 8]);
    const short8 b0 = *reinterpret_cast<const short8*>(&B_l[(wn * 32 + fr) * 40 + fg * 8]);
    const short8 b1 = *reinterpret_cast<const short8*>(&B_l[(wn * 32 + 16 + fr) * 40 + fg * 8]);
    acc[0][0] = __builtin_amdgcn_mfma_f32_16x16x32_bf16(a0, b0, acc[0][0], 0, 0, 0);
    acc[0][1] = __builtin_amdgcn_mfma_f32_16x16x32_bf16(a0, b1, acc[0][1], 0, 0, 0);
    acc[1][0] = __builtin_amdgcn_mfma_f32_16x16x32_bf16(a1, b0, acc[1][0], 0, 0, 0);
    acc[1][1] = __builtin_amdgcn_mfma_f32_16x16x32_bf16(a1, b1, acc[1][1], 0, 0, 0);
    __syncthreads();
  }
#pragma unroll
  for (int i2 = 0; i2 < 2; ++i2)
#pragma unroll
    for (int j2 = 0; j2 < 2; ++j2)
#pragma unroll
      for (int e = 0; e < 4; ++e) {
        const int row = mt * 64 + wm * 32 + i2 * 16 + fg * 4 + e;  // C row = (l>>4)*4+reg
        const int col = nt * 64 + wn * 32 + j2 * 16 + fr;          // C col = lane&15
        C_part[((long)kz * 4608 + row) * 256 + col] = acc[i2][j2][e];
      }
}

// ---------------- combine K-split partials + bias + squash -> u [8,18432,8] ----------------
__global__ __launch_bounds__(256) void combine_k(const float* __restrict__ C_part,
                                                 const float* __restrict__ prim_b,
                                                 float* __restrict__ u) {
  const int cap = blockIdx.x * 256 + threadIdx.x;  // 576*256 = 147456 exact
  const int b = cap / 18432, r = cap % 18432;
  const int g = r / 576, yx = r % 576;
  const long m = (long)b * 576 + yx;
  float pv[8];
#pragma unroll
  for (int e = 0; e < 8; ++e) pv[e] = prim_b[g * 8 + e];
#pragma unroll
  for (int kz = 0; kz < 4; ++kz) {
    const float4* cp = (const float4*)(C_part + ((long)kz * 4608 + m) * 256 + g * 8);
    const float4 f0 = cp[0], f1 = cp[1];
    pv[0] += f0.x; pv[1] += f0.y; pv[2] += f0.z; pv[3] += f0.w;
    pv[4] += f1.x; pv[5] += f1.y; pv[6] += f1.z; pv[7] += f1.w;
  }
  float sn = 0.f;
#pragma unroll
  for (int e = 0; e < 8; ++e) sn += pv[e] * pv[e];
  const float f = sn / (1.f + sn) / (sqrtf(sn) + 1e-8f);
  float4 o0, o1;
  o0.x = pv[0] * f; o0.y = pv[1] * f; o0.z = pv[2] * f; o0.w = pv[3] * f;
  o1.x = pv[4] * f; o1.y = pv[5] * f; o1.z = pv[6] * f; o1.w = pv[7] * f;
  float4* up = (float4*)(u + (long)cap * 8);
  up[0] = o0; up[1] = o1;
}

// ---------------- routing pass v2 ----------------
// 576 blocks x 512 threads. wave = b (8 waves/block); lane = nq(2 bits)*16 + d(4 bits).
// Each thread owns 13 classes (n = nq*13+q, padded 52). Per-thread arrays = 13 (no spill).
// logits = dot_d(u_hat, vsum) via 4 shfl_xor; softmax over n via in-thread + 2 shfl_xor;
// S accumulated in regs over 32 i-rows, one partial per block.
__global__ __launch_bounds__(512, 4) void route_pass(const float* __restrict__ W,
                                                     const float* __restrict__ u,
                                                     const float* __restrict__ vsum,
                                                     float* __restrict__ S_part) {
  const int t = threadIdx.x;
  const int b = t >> 6;
  const int lane = t & 63;
  const int d = lane & 15, nq = lane >> 4;
  const int qmax = (nq == 3) ? 11 : 13;  // n in [39,49] for nq=3
  int nn[13];
  float vs[13], Sa[13], uh[13], lg[13];
#pragma unroll
  for (int q = 0; q < 13; ++q) {
    const int n = nq * 13 + q;
    const bool valid = n < 50;
    nn[q] = valid ? n : 49;  // clamp so loads stay in-bounds
    vs[q] = valid ? vsum[(b * 50 + n) * 16 + d] : 0.f;
    Sa[q] = 0.f;
  }
  const int bi = blockIdx.x;
  for (int ii = 0; ii < 32; ++ii) {
    const int i = bi * 32 + ii;
    const float4* up = (const float4*)(u + ((long)b * 18432 + i) * 8);
    const float4 u0 = up[0], u1 = up[1];
    const float* Wi = W + (long)i * 128 + d * 8;
#pragma unroll
    for (int q = 0; q < 13; ++q) {
      const float4* wp = (const float4*)(Wi + (long)nn[q] * 2359296);
      const float4 w0 = wp[0], w1 = wp[1];
      const float s = w0.x * u0.x + w0.y * u0.y + w0.z * u0.z + w0.w * u0.w +
                      w1.x * u1.x + w1.y * u1.y + w1.z * u1.z + w1.w * u1.w;
      uh[q] = s;
      float v = s * vs[q];
      v += __shfl_xor(v, 1);   // reduce over d (lane bits 0..3)
      v += __shfl_xor(v, 2);
      v += __shfl_xor(v, 4);
      v += __shfl_xor(v, 8);
      lg[q] = (q < qmax) ? v : -1e30f;
    }
    float mx = lg[0];
#pragma unroll
    for (int q = 1; q < 13; ++q) mx = fmaxf(mx, lg[q]);
    mx = fmaxf(mx, __shfl_xor(mx, 16));  // combine nq groups (lane bits 4,5)
    mx = fmaxf(mx, __shfl_xor(mx, 32));
    float sm = 0.f;
#pragma unroll
    for (int q = 0; q < 13; ++q) {
      const float e = __expf(lg[q] - mx);
      lg[q] = e;
      sm += e;
    }
    sm += __shfl_xor(sm, 16);
    sm += __shfl_xor(sm, 32);
    const float inv = 1.f / sm;
#pragma unroll
    for (int q = 0; q < 13; ++q) Sa[q] = fmaf(lg[q] * inv, uh[q], Sa[q]);
  }
  float* Sp = S_part + ((long)bi * 8 + b) * 800;
#pragma unroll
  for (int q = 0; q < 13; ++q)
    if (q < qmax) Sp[(nq * 13 + q) * 16 + d] = Sa[q];
}

// ---------------- reduce 576 partials -> v = squash(S); vsum += v or v3 = v ------
__global__ __launch_bounds__(256) void route_reduce(const float* __restrict__ S_part,
                                                    float* __restrict__ vsum,
                                                    float* __restrict__ v3,
                                                    const int pass) {
  __shared__ float lds[256];
  const int bn = blockIdx.x;  // 400 = b*50+n
  const int b = bn / 50, n = bn % 50;
  const int t = threadIdx.x;
  const int kk = t >> 4, dd = t & 15;
  float s = 0.f;
  const float* p = S_part + (long)b * 800 + n * 16 + dd;
  for (int j = kk; j < 576; j += 16) s += p[(long)j * 6400];
  lds[t] = s;
  __syncthreads();
  for (int off = 128; off >= 16; off >>= 1) {
    if (t < off) lds[t] += lds[t + off];
    __syncthreads();
  }
  if (t < 16) {
    const float S = lds[t];
    float sq = S * S;
    sq += __shfl_xor(sq, 1);
    sq += __shfl_xor(sq, 2);
    sq += __shfl_xor(sq, 4);
    sq += __shfl_xor(sq, 8);
    const float f = sq / (1.f + sq) / (sqrtf(sq) + 1e-8f);
    const float v = S * f;
    const int o = bn * 16 + t;
    if (pass < 3) vsum[o] += v;
    else v3[o] = v;
  }
}

// ---------------- preds, argmax, select masked capsule ----------------
__global__ __launch_bounds__(512) void head_k(const float* __restrict__ v3,
                                              float* __restrict__ out,
                                              float* __restrict__ selv,
                                              int* __restrict__ idxs) {
  __shared__ float pl[400];
  const int t = threadIdx.x;
  if (t < 400) {
    const float4* vp = (const float4*)(v3 + t * 16);
    const float4 a = vp[0], b = vp[1], c = vp[2], d = vp[3];
    const float s = a.x * a.x + a.y * a.y + a.z * a.z + a.w * a.w +
                    b.x * b.x + b.y * b.y + b.z * b.z + b.w * b.w +
                    c.x * c.x + c.y * c.y + c.z * c.z + c.w * c.w +
                    d.x * d.x + d.y * d.y + d.z * d.z + d.w * d.w;
    const float p = sqrtf(s);
    out[t] = p;   // preds, flat [8,50]
    pl[t] = p;
  }
  __syncthreads();
  if (t < 8) {
    float best = -1e30f;
    int bi = 0;
    for (int n = 0; n < 50; ++n) {
      const float p = pl[t * 50 + n];
      if (p > best) { best = p; bi = n; }  // first max, matches argmax
    }
    idxs[t] = bi;
    for (int k = 0; k < 16; ++k) selv[t * 16 + k] = v3[(t * 50 + bi) * 16 + k];
  }
}

// ---------------- decoder ----------------
__global__ __launch_bounds__(512) void d1_k(const float* __restrict__ selv,
                                            const int* __restrict__ idxs,
                                            const float* __restrict__ d1w,
                                            const float* __restrict__ d1b,
                                            float* __restrict__ r1) {
  const int b = blockIdx.x, j = threadIdx.x;
  const int idx = idxs[b];
  const float* wr = d1w + j * 800 + idx * 16;
  float acc = d1b[j];
#pragma unroll
  for (int k = 0; k < 16; ++k) acc = fmaf(selv[b * 16 + k], wr[k], acc);
  r1[b * 512 + j] = acc > 0.f ? acc : 0.f;
}

__global__ __launch_bounds__(256) void d2_k(const float* __restrict__ r1,
                                            const float* __restrict__ d2w,
                                            const float* __restrict__ d2b,
                                            float* __restrict__ r2) {
  __shared__ float rl[512];
  const int b = blockIdx.y;
  const int j = blockIdx.x * 256 + threadIdx.x;
  for (int r = threadIdx.x; r < 512; r += 256) rl[r] = r1[b * 512 + r];
  __syncthreads();
  const float4* wr = (const float4*)(d2w + (long)j * 512);
  float acc = d2b[j];
  for (int k4 = 0; k4 < 128; ++k4) {
    const float4 w = wr[k4];
    acc += w.x * rl[k4 * 4] + w.y * rl[k4 * 4 + 1] + w.z * rl[k4 * 4 + 2] + w.w * rl[k4 * 4 + 3];
  }
  r2[b * 1024 + j] = acc > 0.f ? acc : 0.f;
}

__global__ __launch_bounds__(256) void d3_k(const float* __restrict__ r2,
                                            const float* __restrict__ d3w,
                                            const float* __restrict__ d3b,
                                            float* __restrict__ out) {
  __shared__ float rl[8192];
  const int j = blockIdx.x * 256 + threadIdx.x;
  float4* rl4 = (float4*)rl;
  for (int r = threadIdx.x; r < 2048; r += 256) rl4[r] = ((const float4*)r2)[r];
  __syncthreads();
  float acc[8];
  const float bv = d3b[j];
#pragma unroll
  for (int b = 0; b < 8; ++b) acc[b] = bv;
  const float4* wr = (const float4*)d3w + (long)j * 256;
  for (int k4 = 0; k4 < 256; ++k4) {
    const float4 w = wr[k4];
#pragma unroll
    for (int b = 0; b < 8; ++b) {
      const int o = b * 1024 + k4 * 4;
      acc[b] += w.x * rl[o] + w.y * rl[o + 1] + w.z * rl[o + 2] + w.w * rl[o + 3];
    }
  }
#pragma unroll
  for (int b = 0; b < 8; ++b)
    out[400 + b * 12288 + j] = 1.f / (1.f + __expf(-acc[b]));
}

extern "C" void kernel_launch(void* const* d_in, const int* in_sizes, int n_in,
                              void* d_out, int out_size, void* d_ws, size_t ws_size,
                              hipStream_t stream) {
  const float* x   = (const float*)d_in[0];
  const float* c1w = (const float*)d_in[1];
  const float* c1b = (const float*)d_in[2];
  const float* pw  = (const float*)d_in[3];
  const float* pb  = (const float*)d_in[4];
  const float* W   = (const float*)d_in[5];
  const float* d1w = (const float*)d_in[6];
  const float* d1b = (const float*)d_in[7];
  const float* d2w = (const float*)d_in[8];
  const float* d2b = (const float*)d_in[9];
  const float* d3w = (const float*)d_in[10];
  const float* d3b = (const float*)d_in[11];
  float* out = (float*)d_out;

  char* wsb = (char*)d_ws;
  size_t off = 0;
  auto alloc = [&](size_t bytes) -> char* {
    char* p = wsb + off;
    off += (bytes + 255) & ~(size_t)255;
    return p;
  };
  unsigned short* h_bf   = (unsigned short*)alloc(12845056);  // bf16 h
  unsigned short* wbf    = (unsigned short*)alloc(10616832);  // bf16 tiled prim_w
  unsigned*       offt   = (unsigned*)alloc(82944);
  // C_part (4 K-split partials, 18.9 MB) and S_part (576 partials, 14.75 MB) alias:
  // C_part is dead after combine_k, before the first route_pass.
  char*           bigA   = alloc(18874368);
  float*          C_part = (float*)bigA;
  float*          S_part = (float*)bigA;
  float*          u      = (float*)alloc(4718592);            // squashed caps
  float*          vsum   = (float*)alloc(25600);
  float*          v3     = (float*)alloc(25600);
  float*          selv   = (float*)alloc(512);
  int*            idxs   = (int*)alloc(64);
  float*          r1     = (float*)alloc(16384);
  float*          r2     = (float*)alloc(32768);
  if (off > ws_size) return;  // fail loudly (outputs stay poisoned)

  offtab_k<<<81, 256, 0, stream>>>(offt);
  wconv_k<<<2592, 256, 0, stream>>>(pw, wbf);
  conv1_k<<<2048, 256, 0, stream>>>(x, c1w, c1b, h_bf);
  prim_gemm<<<dim3(72, 4, 4), 256, 0, stream>>>(h_bf, wbf, offt, C_part);
  combine_k<<<576, 256, 0, stream>>>(C_part, pb, u);
  hipMemsetAsync(vsum, 0, 25600, stream);
  for (int pass = 1; pass <= 3; ++pass) {
    route_pass<<<576, 512, 0, stream>>>(W, u, vsum, S_part);
    route_reduce<<<400, 256, 0, stream>>>(S_part, vsum, v3, pass);
  }
  head_k<<<1, 512, 0, stream>>>(v3, out, selv, idxs);
  d1_k<<<8, 512, 0, stream>>>(selv, idxs, d1w, d1b, r1);
  d2_k<<<dim3(4, 8), 256, 0, stream>>>(r1, d2w, d2b, r2);
  d3_k<<<48, 256, 0, stream>>>(r2, d3w, d3b, out);
}

// Round 3
// 1303.520 us; speedup vs baseline: 2.3080x; 1.1869x over previous
//
#include <hip/hip_runtime.h>

typedef short short8 __attribute__((ext_vector_type(8)));
typedef float f32x4 __attribute__((ext_vector_type(4)));

__device__ __forceinline__ unsigned short f2bf(float f) {
  union { float f; unsigned u; } a; a.f = f;
  unsigned r = a.u + 0x7fffu + ((a.u >> 16) & 1u);
  return (unsigned short)(r >> 16);
}

__device__ __forceinline__ float bfhi(unsigned w) {  // high bf16 of word
  union { unsigned u; float f; } q; q.u = w & 0xffff0000u; return q.f;
}
__device__ __forceinline__ float bflo(unsigned w) {  // low bf16 of word
  union { unsigned u; float f; } q; q.u = w << 16; return q.f;
}

// ---------------- tap offset table: off[k] = ci*3136 + ky*56 + kx ----------------
__global__ void offtab_k(unsigned* __restrict__ off_tab) {
  const int k = blockIdx.x * 256 + threadIdx.x;  // 81*256 = 20736 exact
  const int ci = k / 81, rr = k % 81;
  const int ky = rr / 9, kx = rr % 9;
  off_tab[k] = (unsigned)(ci * 3136 + ky * 56 + kx);
}

// ---------------- prim_w fp32 -> bf16 tiled [kb][co][8] ----------------
__global__ __launch_bounds__(256) void wconv_k(const float* __restrict__ pw,
                                               unsigned short* __restrict__ wbf) {
  const int kb = blockIdx.x, co = threadIdx.x;  // 2592 blocks
  const float4* src = (const float4*)(pw + (long)co * 20736 + kb * 8);
  const float4 a = src[0], b = src[1];
  union { unsigned short s[8]; short8 v; } o;
  o.s[0] = f2bf(a.x); o.s[1] = f2bf(a.y); o.s[2] = f2bf(a.z); o.s[3] = f2bf(a.w);
  o.s[4] = f2bf(b.x); o.s[5] = f2bf(b.y); o.s[6] = f2bf(b.z); o.s[7] = f2bf(b.w);
  *reinterpret_cast<short8*>(&wbf[((long)kb * 256 + co) * 8]) = o.v;
}

// ---------------- routing W fp32 -> bf16 (same [n][i][d][e] layout) ----------------
__global__ __launch_bounds__(512) void wcvt_k(const float* __restrict__ W,
                                              unsigned short* __restrict__ Wbf) {
  const long unit = (long)blockIdx.x * 512 + threadIdx.x;  // 28800*512 = 14,745,600 exact
  const float4* src = (const float4*)(W + unit * 8);
  const float4 a = src[0], b = src[1];
  union { unsigned short s[8]; uint4 v; } o;
  o.s[0] = f2bf(a.x); o.s[1] = f2bf(a.y); o.s[2] = f2bf(a.z); o.s[3] = f2bf(a.w);
  o.s[4] = f2bf(b.x); o.s[5] = f2bf(b.y); o.s[6] = f2bf(b.z); o.s[7] = f2bf(b.w);
  ((uint4*)Wbf)[unit] = o.v;
}

// ---------------- conv1: [8,3,64,64] -> bf16 h [8,256,56,56], relu ----------------
__global__ __launch_bounds__(256) void conv1_k(const float* __restrict__ x,
                                               const float* __restrict__ w,
                                               const float* __restrict__ bias,
                                               unsigned short* __restrict__ h_bf) {
  __shared__ float xl[12288];
  __shared__ float wl[244];
  const int blk = blockIdx.x;          // 2048 = 8b * 256co
  const int b = blk >> 8, co = blk & 255;
  const int t = threadIdx.x;
  const float4* xb = (const float4*)(x + b * 12288);
  float4* xl4 = (float4*)xl;
  for (int r = t; r < 3072; r += 256) xl4[r] = xb[r];
  for (int r = t; r < 243; r += 256) wl[r] = w[co * 243 + r];
  __syncthreads();
  if (t >= 224) return;
  const int ox = t % 56, oy0 = (t / 56) * 14;
  float acc[14];
#pragma unroll
  for (int j = 0; j < 14; ++j) acc[j] = 0.f;
  for (int ci = 0; ci < 3; ++ci)
    for (int kx = 0; kx < 9; ++kx) {
      const int base = ci * 4096 + oy0 * 64 + ox + kx;
      float win[22];
#pragma unroll
      for (int q = 0; q < 22; ++q) win[q] = xl[base + q * 64];
#pragma unroll
      for (int ky = 0; ky < 9; ++ky) {
        const float wv = wl[ci * 81 + ky * 9 + kx];
#pragma unroll
        for (int j = 0; j < 14; ++j) acc[j] = fmaf(wv, win[j + ky], acc[j]);
      }
    }
  const float bv = bias[co];
  unsigned short* hp = h_bf + (((long)b * 256 + co) * 56 + oy0) * 56 + ox;
#pragma unroll
  for (int j = 0; j < 14; ++j) {
    float v = acc[j] + bv;
    v = v > 0.f ? v : 0.f;
    hp[j * 56] = f2bf(v);
  }
}

// ---------------- prim conv implicit GEMM: C[m=4608][co=256], K=20736 ----------------
__global__ __launch_bounds__(256) void prim_gemm(const unsigned short* __restrict__ h_bf,
                                                 const unsigned short* __restrict__ wbf,
                                                 const unsigned* __restrict__ off_tab,
                                                 float* __restrict__ C_part) {
  __shared__ unsigned short A_l[64 * 40];
  __shared__ unsigned short B_l[64 * 40];
  const int t = threadIdx.x;
  const int lane = t & 63, kkg = t >> 6;
  const int mt = blockIdx.x, nt = blockIdx.y, kz = blockIdx.z;
  const int m = mt * 64 + lane;
  const int b = m / 576, yx = m % 576;
  const int oy = yx / 24, ox = yx % 24;
  const long base_p = (long)b * 802816 + oy * 112 + ox * 2;
  const int cog = nt * 64 + lane;
  const int k0 = kz * 5184;
  const int wm = kkg & 1, wn = kkg >> 1;
  const int fr = lane & 15, fg = lane >> 4;
  f32x4 acc[2][2];
#pragma unroll
  for (int a = 0; a < 2; ++a)
#pragma unroll
    for (int c = 0; c < 2; ++c)
#pragma unroll
      for (int e = 0; e < 4; ++e) acc[a][c][e] = 0.f;
  for (int kt = 0; kt < 162; ++kt) {
    const int k = k0 + kt * 32;
    union { unsigned short s[8]; short8 v; } au;
#pragma unroll
    for (int j = 0; j < 8; ++j) {
      const unsigned o = off_tab[k + kkg * 8 + j];
      au.s[j] = h_bf[base_p + o];
    }
    *reinterpret_cast<short8*>(&A_l[lane * 40 + kkg * 8]) = au.v;
    const short8 bvv = *reinterpret_cast<const short8*>(
        &wbf[(((long)(k >> 3) + kkg) * 256 + cog) * 8]);
    *reinterpret_cast<short8*>(&B_l[lane * 40 + kkg * 8]) = bvv;
    __syncthreads();
    const short8 a0 = *reinterpret_cast<const short8*>(&A_l[(wm * 32 + fr) * 40 + fg * 8]);
    const short8 a1 = *reinterpret_cast<const short8*>(&A_l[(wm * 32 + 16 + fr) * 40 + fg * 8]);
    const short8 b0 = *reinterpret_cast<const short8*>(&B_l[(wn * 32 + fr) * 40 + fg * 8]);
    const short8 b1 = *reinterpret_cast<const short8*>(&B_l[(wn * 32 + 16 + fr) * 40 + fg * 8]);
    acc[0][0] = __builtin_amdgcn_mfma_f32_16x16x32_bf16(a0, b0, acc[0][0], 0, 0, 0);
    acc[0][1] = __builtin_amdgcn_mfma_f32_16x16x32_bf16(a0, b1, acc[0][1], 0, 0, 0);
    acc[1][0] = __builtin_amdgcn_mfma_f32_16x16x32_bf16(a1, b0, acc[1][0], 0, 0, 0);
    acc[1][1] = __builtin_amdgcn_mfma_f32_16x16x32_bf16(a1, b1, acc[1][1], 0, 0, 0);
    __syncthreads();
  }
#pragma unroll
  for (int i2 = 0; i2 < 2; ++i2)
#pragma unroll
    for (int j2 = 0; j2 < 2; ++j2)
#pragma unroll
      for (int e = 0; e < 4; ++e) {
        const int row = mt * 64 + wm * 32 + i2 * 16 + fg * 4 + e;
        const int col = nt * 64 + wn * 32 + j2 * 16 + fr;
        C_part[((long)kz * 4608 + row) * 256 + col] = acc[i2][j2][e];
      }
}

// ---------------- combine K-split partials + bias + squash -> u [8,18432,8] ----------------
__global__ __launch_bounds__(256) void combine_k(const float* __restrict__ C_part,
                                                 const float* __restrict__ prim_b,
                                                 float* __restrict__ u) {
  const int cap = blockIdx.x * 256 + threadIdx.x;
  const int b = cap / 18432, r = cap % 18432;
  const int g = r / 576, yx = r % 576;
  const long m = (long)b * 576 + yx;
  float pv[8];
#pragma unroll
  for (int e = 0; e < 8; ++e) pv[e] = prim_b[g * 8 + e];
#pragma unroll
  for (int kz = 0; kz < 4; ++kz) {
    const float4* cp = (const float4*)(C_part + ((long)kz * 4608 + m) * 256 + g * 8);
    const float4 f0 = cp[0], f1 = cp[1];
    pv[0] += f0.x; pv[1] += f0.y; pv[2] += f0.z; pv[3] += f0.w;
    pv[4] += f1.x; pv[5] += f1.y; pv[6] += f1.z; pv[7] += f1.w;
  }
  float sn = 0.f;
#pragma unroll
  for (int e = 0; e < 8; ++e) sn += pv[e] * pv[e];
  const float f = sn / (1.f + sn) / (sqrtf(sn) + 1e-8f);
  float4 o0, o1;
  o0.x = pv[0] * f; o0.y = pv[1] * f; o0.z = pv[2] * f; o0.w = pv[3] * f;
  o1.x = pv[4] * f; o1.y = pv[5] * f; o1.z = pv[6] * f; o1.w = pv[7] * f;
  float4* up = (float4*)(u + (long)cap * 8);
  up[0] = o0; up[1] = o1;
}

// ---------------- routing pass v3: bf16 W, lane = class ----------------
// 576 blocks x 512 thr (8 waves). wave = b; lane = n (50 active). Block owns 32 i.
// W rows staged via LDS (shared by 8 b-waves), chunk = 2 i (1600 x 16B units),
// XOR-swizzled 16B slots -> conflict-even ds_read_b128. Register prefetch of
// next chunk issued before compute. Logit dot is in-thread; softmax over n via
// 64-lane butterflies (lanes 50-63 masked).
__global__ __launch_bounds__(512, 4) void route_bf16(const uint4* __restrict__ Wb4,
                                                     const float* __restrict__ u,
                                                     const float* __restrict__ vsum,
                                                     float* __restrict__ S_part) {
  __shared__ uint4 lds4[1600];
  const int t = threadIdx.x;
  const int b = t >> 6, lane = t & 63;
  const bool vn = lane < 50;
  const int nr = vn ? lane : 49;
  const int nxor = nr & 15;
  const int bi = blockIdx.x;
  const int i_base = bi * 32;

  float vs[16], Sa[16];
#pragma unroll
  for (int d = 0; d < 16; ++d) {
    vs[d] = vsum[(b * 50 + nr) * 16 + d];
    Sa[d] = 0.f;
  }

  const int idx0 = t, idx1 = t + 512, idx2 = t + 1024, idx3 = t + 1536;
  const bool g2 = t < 576, g3 = t < 64;  // 1600 = 512*3 + 64
  auto gload = [&](int idx, int i0) -> uint4 {
    const int n = idx >> 5, i2 = (idx >> 4) & 1, c = idx & 15;
    return Wb4[(long)(n * 18432 + i0 + i2) * 16 + c];
  };
  auto lput = [&](int idx, uint4 v) {
    const int n = idx >> 5, i2 = (idx >> 4) & 1, c = idx & 15;
    lds4[n * 32 + i2 * 16 + (c ^ (n & 15))] = v;
  };
  uint4 r0, r1, r2, r3;
  const uint4 zz = make_uint4(0, 0, 0, 0);
  r0 = gload(idx0, i_base);
  r1 = gload(idx1, i_base);
  r2 = g2 ? gload(idx2, i_base) : zz;
  r3 = g3 ? gload(idx3, i_base) : zz;

  for (int ch = 0; ch < 16; ++ch) {
    __syncthreads();  // previous chunk's LDS reads complete
    lput(idx0, r0);
    lput(idx1, r1);
    if (g2) lput(idx2, r2);
    if (g3) lput(idx3, r3);
    if (ch < 15) {  // issue next chunk's global loads now; latency hides under compute
      const int ni = i_base + (ch + 1) * 2;
      r0 = gload(idx0, ni);
      r1 = gload(idx1, ni);
      if (g2) r2 = gload(idx2, ni);
      if (g3) r3 = gload(idx3, ni);
    }
    __syncthreads();
#pragma unroll
    for (int ii = 0; ii < 2; ++ii) {
      const int i = i_base + ch * 2 + ii;
      const float4* up = (const float4*)(u + ((long)b * 18432 + i) * 8);
      const float4 ua = up[0], ub = up[1];
      const uint4* lrow = &lds4[nr * 32 + ii * 16];
      float uh[16];
      float lg = 0.f;
#pragma unroll
      for (int d = 0; d < 16; ++d) {
        const uint4 w = lrow[d ^ nxor];
        float acc;
        acc = bflo(w.x) * ua.x;
        acc = fmaf(bfhi(w.x), ua.y, acc);
        acc = fmaf(bflo(w.y), ua.z, acc);
        acc = fmaf(bfhi(w.y), ua.w, acc);
        acc = fmaf(bflo(w.z), ub.x, acc);
        acc = fmaf(bfhi(w.z), ub.y, acc);
        acc = fmaf(bflo(w.w), ub.z, acc);
        acc = fmaf(bfhi(w.w), ub.w, acc);
        uh[d] = acc;
        lg = fmaf(acc, vs[d], lg);
      }
      lg = vn ? lg : -1e30f;
      float mx = lg;
      mx = fmaxf(mx, __shfl_xor(mx, 1));
      mx = fmaxf(mx, __shfl_xor(mx, 2));
      mx = fmaxf(mx, __shfl_xor(mx, 4));
      mx = fmaxf(mx, __shfl_xor(mx, 8));
      mx = fmaxf(mx, __shfl_xor(mx, 16));
      mx = fmaxf(mx, __shfl_xor(mx, 32));
      float p = vn ? __expf(lg - mx) : 0.f;
      float sm = p;
      sm += __shfl_xor(sm, 1);
      sm += __shfl_xor(sm, 2);
      sm += __shfl_xor(sm, 4);
      sm += __shfl_xor(sm, 8);
      sm += __shfl_xor(sm, 16);
      sm += __shfl_xor(sm, 32);
      const float sc = p / sm;
#pragma unroll
      for (int d = 0; d < 16; ++d) Sa[d] = fmaf(sc, uh[d], Sa[d]);
    }
  }
  if (vn) {
    float* Sp = S_part + (long)bi * 6400 + b * 800 + lane * 16;
#pragma unroll
    for (int d = 0; d < 16; ++d) Sp[d] = Sa[d];
  }
}

// ---------------- routing pass (fp32 fallback, proven) ----------------
__global__ __launch_bounds__(512, 4) void route_pass_f32(const float* __restrict__ W,
                                                         const float* __restrict__ u,
                                                         const float* __restrict__ vsum,
                                                         float* __restrict__ S_part) {
  const int t = threadIdx.x;
  const int b = t >> 6;
  const int lane = t & 63;
  const int d = lane & 15, nq = lane >> 4;
  const int qmax = (nq == 3) ? 11 : 13;
  int nn[13];
  float vs[13], Sa[13], uh[13], lg[13];
#pragma unroll
  for (int q = 0; q < 13; ++q) {
    const int n = nq * 13 + q;
    const bool valid = n < 50;
    nn[q] = valid ? n : 49;
    vs[q] = valid ? vsum[(b * 50 + n) * 16 + d] : 0.f;
    Sa[q] = 0.f;
  }
  const int bi = blockIdx.x;
  for (int ii = 0; ii < 32; ++ii) {
    const int i = bi * 32 + ii;
    const float4* up = (const float4*)(u + ((long)b * 18432 + i) * 8);
    const float4 u0 = up[0], u1 = up[1];
    const float* Wi = W + (long)i * 128 + d * 8;
#pragma unroll
    for (int q = 0; q < 13; ++q) {
      const float4* wp = (const float4*)(Wi + (long)nn[q] * 2359296);
      const float4 w0 = wp[0], w1 = wp[1];
      const float s = w0.x * u0.x + w0.y * u0.y + w0.z * u0.z + w0.w * u0.w +
                      w1.x * u1.x + w1.y * u1.y + w1.z * u1.z + w1.w * u1.w;
      uh[q] = s;
      float v = s * vs[q];
      v += __shfl_xor(v, 1);
      v += __shfl_xor(v, 2);
      v += __shfl_xor(v, 4);
      v += __shfl_xor(v, 8);
      lg[q] = (q < qmax) ? v : -1e30f;
    }
    float mx = lg[0];
#pragma unroll
    for (int q = 1; q < 13; ++q) mx = fmaxf(mx, lg[q]);
    mx = fmaxf(mx, __shfl_xor(mx, 16));
    mx = fmaxf(mx, __shfl_xor(mx, 32));
    float sm = 0.f;
#pragma unroll
    for (int q = 0; q < 13; ++q) {
      const float e = __expf(lg[q] - mx);
      lg[q] = e;
      sm += e;
    }
    sm += __shfl_xor(sm, 16);
    sm += __shfl_xor(sm, 32);
    const float inv = 1.f / sm;
#pragma unroll
    for (int q = 0; q < 13; ++q) Sa[q] = fmaf(lg[q] * inv, uh[q], Sa[q]);
  }
  float* Sp = S_part + ((long)bi * 8 + b) * 800;
#pragma unroll
  for (int q = 0; q < 13; ++q)
    if (q < qmax) Sp[(nq * 13 + q) * 16 + d] = Sa[q];
}

// ---------------- reduce 576 partials -> v = squash(S); vsum += v or v3 = v ------
__global__ __launch_bounds__(256) void route_reduce(const float* __restrict__ S_part,
                                                    float* __restrict__ vsum,
                                                    float* __restrict__ v3,
                                                    const int pass) {
  __shared__ float lds[256];
  const int bn = blockIdx.x;  // 400 = b*50+n
  const int b = bn / 50, n = bn % 50;
  const int t = threadIdx.x;
  const int kk = t >> 4, dd = t & 15;
  float s = 0.f;
  const float* p = S_part + (long)b * 800 + n * 16 + dd;
  for (int j = kk; j < 576; j += 16) s += p[(long)j * 6400];
  lds[t] = s;
  __syncthreads();
  for (int off = 128; off >= 16; off >>= 1) {
    if (t < off) lds[t] += lds[t + off];
    __syncthreads();
  }
  if (t < 16) {
    const float S = lds[t];
    float sq = S * S;
    sq += __shfl_xor(sq, 1);
    sq += __shfl_xor(sq, 2);
    sq += __shfl_xor(sq, 4);
    sq += __shfl_xor(sq, 8);
    const float f = sq / (1.f + sq) / (sqrtf(sq) + 1e-8f);
    const float v = S * f;
    const int o = bn * 16 + t;
    if (pass < 3) vsum[o] += v;
    else v3[o] = v;
  }
}

// ---------------- preds, argmax, select masked capsule ----------------
__global__ __launch_bounds__(512) void head_k(const float* __restrict__ v3,
                                              float* __restrict__ out,
                                              float* __restrict__ selv,
                                              int* __restrict__ idxs) {
  __shared__ float pl[400];
  const int t = threadIdx.x;
  if (t < 400) {
    const float4* vp = (const float4*)(v3 + t * 16);
    const float4 a = vp[0], b = vp[1], c = vp[2], d = vp[3];
    const float s = a.x * a.x + a.y * a.y + a.z * a.z + a.w * a.w +
                    b.x * b.x + b.y * b.y + b.z * b.z + b.w * b.w +
                    c.x * c.x + c.y * c.y + c.z * c.z + c.w * c.w +
                    d.x * d.x + d.y * d.y + d.z * d.z + d.w * d.w;
    const float p = sqrtf(s);
    out[t] = p;
    pl[t] = p;
  }
  __syncthreads();
  if (t < 8) {
    float best = -1e30f;
    int bi = 0;
    for (int n = 0; n < 50; ++n) {
      const float p = pl[t * 50 + n];
      if (p > best) { best = p; bi = n; }
    }
    idxs[t] = bi;
    for (int k = 0; k < 16; ++k) selv[t * 16 + k] = v3[(t * 50 + bi) * 16 + k];
  }
}

// ---------------- decoder ----------------
__global__ __launch_bounds__(512) void d1_k(const float* __restrict__ selv,
                                            const int* __restrict__ idxs,
                                            const float* __restrict__ d1w,
                                            const float* __restrict__ d1b,
                                            float* __restrict__ r1) {
  const int b = blockIdx.x, j = threadIdx.x;
  const int idx = idxs[b];
  const float* wr = d1w + j * 800 + idx * 16;
  float acc = d1b[j];
#pragma unroll
  for (int k = 0; k < 16; ++k) acc = fmaf(selv[b * 16 + k], wr[k], acc);
  r1[b * 512 + j] = acc > 0.f ? acc : 0.f;
}

__global__ __launch_bounds__(256) void d2_k(const float* __restrict__ r1,
                                            const float* __restrict__ d2w,
                                            const float* __restrict__ d2b,
                                            float* __restrict__ r2) {
  __shared__ float rl[512];
  const int b = blockIdx.y;
  const int j = blockIdx.x * 256 + threadIdx.x;
  for (int r = threadIdx.x; r < 512; r += 256) rl[r] = r1[b * 512 + r];
  __syncthreads();
  const float4* wr = (const float4*)(d2w + (long)j * 512);
  float acc = d2b[j];
  for (int k4 = 0; k4 < 128; ++k4) {
    const float4 w = wr[k4];
    acc += w.x * rl[k4 * 4] + w.y * rl[k4 * 4 + 1] + w.z * rl[k4 * 4 + 2] + w.w * rl[k4 * 4 + 3];
  }
  r2[b * 1024 + j] = acc > 0.f ? acc : 0.f;
}

__global__ __launch_bounds__(256) void d3_k(const float* __restrict__ r2,
                                            const float* __restrict__ d3w,
                                            const float* __restrict__ d3b,
                                            float* __restrict__ out) {
  __shared__ float rl[8192];
  const int j = blockIdx.x * 256 + threadIdx.x;
  float4* rl4 = (float4*)rl;
  for (int r = threadIdx.x; r < 2048; r += 256) rl4[r] = ((const float4*)r2)[r];
  __syncthreads();
  float acc[8];
  const float bv = d3b[j];
#pragma unroll
  for (int b = 0; b < 8; ++b) acc[b] = bv;
  const float4* wr = (const float4*)d3w + (long)j * 256;
  for (int k4 = 0; k4 < 256; ++k4) {
    const float4 w = wr[k4];
#pragma unroll
    for (int b = 0; b < 8; ++b) {
      const int o = b * 1024 + k4 * 4;
      acc[b] += w.x * rl[o] + w.y * rl[o + 1] + w.z * rl[o + 2] + w.w * rl[o + 3];
    }
  }
#pragma unroll
  for (int b = 0; b < 8; ++b)
    out[400 + b * 12288 + j] = 1.f / (1.f + __expf(-acc[b]));
}

extern "C" void kernel_launch(void* const* d_in, const int* in_sizes, int n_in,
                              void* d_out, int out_size, void* d_ws, size_t ws_size,
                              hipStream_t stream) {
  const float* x   = (const float*)d_in[0];
  const float* c1w = (const float*)d_in[1];
  const float* c1b = (const float*)d_in[2];
  const float* pw  = (const float*)d_in[3];
  const float* pb  = (const float*)d_in[4];
  const float* W   = (const float*)d_in[5];
  const float* d1w = (const float*)d_in[6];
  const float* d1b = (const float*)d_in[7];
  const float* d2w = (const float*)d_in[8];
  const float* d2b = (const float*)d_in[9];
  const float* d3w = (const float*)d_in[10];
  const float* d3b = (const float*)d_in[11];
  float* out = (float*)d_out;

  char* wsb = (char*)d_ws;
  size_t off = 0;
  auto alloc = [&](size_t bytes) -> char* {
    char* p = wsb + off;
    off += (bytes + 255) & ~(size_t)255;
    return p;
  };
  unsigned short* h_bf   = (unsigned short*)alloc(12845056);  // bf16 h
  unsigned short* wbf    = (unsigned short*)alloc(10616832);  // bf16 tiled prim_w
  unsigned*       offt   = (unsigned*)alloc(82944);
  // C_part (18.9 MB) and S_part (14.75 MB) alias (disjoint lifetimes).
  char*           bigA   = alloc(18874368);
  float*          C_part = (float*)bigA;
  float*          S_part = (float*)bigA;
  float*          u      = (float*)alloc(4718592);
  float*          vsum   = (float*)alloc(25600);
  float*          v3     = (float*)alloc(25600);
  float*          selv   = (float*)alloc(512);
  int*            idxs   = (int*)alloc(64);
  float*          r1     = (float*)alloc(16384);
  float*          r2     = (float*)alloc(32768);
  const size_t off_base = off;
  unsigned short* Wbf    = (unsigned short*)alloc(235929600);  // bf16 routing W
  const bool bf16_route = (off <= ws_size);
  if (off_base > ws_size) return;  // even fallback doesn't fit: outputs stay poisoned

  offtab_k<<<81, 256, 0, stream>>>(offt);
  wconv_k<<<2592, 256, 0, stream>>>(pw, wbf);
  conv1_k<<<2048, 256, 0, stream>>>(x, c1w, c1b, h_bf);
  prim_gemm<<<dim3(72, 4, 4), 256, 0, stream>>>(h_bf, wbf, offt, C_part);
  combine_k<<<576, 256, 0, stream>>>(C_part, pb, u);
  if (bf16_route) wcvt_k<<<28800, 512, 0, stream>>>(W, Wbf);
  hipMemsetAsync(vsum, 0, 25600, stream);
  for (int pass = 1; pass <= 3; ++pass) {
    if (bf16_route)
      route_bf16<<<576, 512, 0, stream>>>((const uint4*)Wbf, u, vsum, S_part);
    else
      route_pass_f32<<<576, 512, 0, stream>>>(W, u, vsum, S_part);
    route_reduce<<<400, 256, 0, stream>>>(S_part, vsum, v3, pass);
  }
  head_k<<<1, 512, 0, stream>>>(v3, out, selv, idxs);
  d1_k<<<8, 512, 0, stream>>>(selv, idxs, d1w, d1b, r1);
  d2_k<<<dim3(4, 8), 256, 0, stream>>>(r1, d2w, d2b, r2);
  d3_k<<<48, 256, 0, stream>>>(r2, d3w, d3b, out);
}

// Round 4
// 771.291 us; speedup vs baseline: 3.9006x; 1.6900x over previous
//
#include <hip/hip_runtime.h>

typedef short short8 __attribute__((ext_vector_type(8)));
typedef float f32x4 __attribute__((ext_vector_type(4)));
typedef _Float16 h2 __attribute__((ext_vector_type(2)));

__device__ __forceinline__ unsigned short f2bf(float f) {
  union { float f; unsigned u; } a; a.f = f;
  unsigned r = a.u + 0x7fffu + ((a.u >> 16) & 1u);
  return (unsigned short)(r >> 16);
}

__device__ __forceinline__ h2 u2h2(unsigned w) {
  union { unsigned u; h2 h; } q; q.u = w; return q.h;
}

#if __has_builtin(__builtin_amdgcn_fdot2)
#define FDOT2(a, b, c) __builtin_amdgcn_fdot2((a), (b), (c), false)
#else
#define FDOT2(a, b, c) ((c) + (float)(a)[0] * (float)(b)[0] + (float)(a)[1] * (float)(b)[1])
#endif

// ---------------- tap offset table: off[k] = ci*3136 + ky*56 + kx ----------------
__global__ void offtab_k(unsigned* __restrict__ off_tab) {
  const int k = blockIdx.x * 256 + threadIdx.x;  // 81*256 = 20736 exact
  const int ci = k / 81, rr = k % 81;
  const int ky = rr / 9, kx = rr % 9;
  off_tab[k] = (unsigned)(ci * 3136 + ky * 56 + kx);
}

// ---------------- prim_w fp32 -> bf16 tiled [kb][co][8] ----------------
__global__ __launch_bounds__(256) void wconv_k(const float* __restrict__ pw,
                                               unsigned short* __restrict__ wbf) {
  const int kb = blockIdx.x, co = threadIdx.x;  // 2592 blocks
  const float4* src = (const float4*)(pw + (long)co * 20736 + kb * 8);
  const float4 a = src[0], b = src[1];
  union { unsigned short s[8]; short8 v; } o;
  o.s[0] = f2bf(a.x); o.s[1] = f2bf(a.y); o.s[2] = f2bf(a.z); o.s[3] = f2bf(a.w);
  o.s[4] = f2bf(b.x); o.s[5] = f2bf(b.y); o.s[6] = f2bf(b.z); o.s[7] = f2bf(b.w);
  *reinterpret_cast<short8*>(&wbf[((long)kb * 256 + co) * 8]) = o.v;
}

// ---------------- routing W fp32 -> f16 (same [n][i][d][e] layout) ----------------
__global__ __launch_bounds__(512) void wcvt_k(const float* __restrict__ W,
                                              uint4* __restrict__ Wh) {
  const long unit = (long)blockIdx.x * 512 + threadIdx.x;  // 28800*512 = 14,745,600 exact
  const float4* src = (const float4*)(W + unit * 8);
  const float4 a = src[0], b = src[1];
  union { _Float16 h[8]; uint4 v; } o;
  o.h[0] = (_Float16)a.x; o.h[1] = (_Float16)a.y; o.h[2] = (_Float16)a.z; o.h[3] = (_Float16)a.w;
  o.h[4] = (_Float16)b.x; o.h[5] = (_Float16)b.y; o.h[6] = (_Float16)b.z; o.h[7] = (_Float16)b.w;
  Wh[unit] = o.v;
}

// ---------------- conv1: [8,3,64,64] -> bf16 h [8,256,56,56], relu ----------------
__global__ __launch_bounds__(256) void conv1_k(const float* __restrict__ x,
                                               const float* __restrict__ w,
                                               const float* __restrict__ bias,
                                               unsigned short* __restrict__ h_bf) {
  __shared__ float xl[12288];
  __shared__ float wl[244];
  const int blk = blockIdx.x;          // 2048 = 8b * 256co
  const int b = blk >> 8, co = blk & 255;
  const int t = threadIdx.x;
  const float4* xb = (const float4*)(x + b * 12288);
  float4* xl4 = (float4*)xl;
  for (int r = t; r < 3072; r += 256) xl4[r] = xb[r];
  for (int r = t; r < 243; r += 256) wl[r] = w[co * 243 + r];
  __syncthreads();
  if (t >= 224) return;
  const int ox = t % 56, oy0 = (t / 56) * 14;
  float acc[14];
#pragma unroll
  for (int j = 0; j < 14; ++j) acc[j] = 0.f;
  for (int ci = 0; ci < 3; ++ci)
    for (int kx = 0; kx < 9; ++kx) {
      const int base = ci * 4096 + oy0 * 64 + ox + kx;
      float win[22];
#pragma unroll
      for (int q = 0; q < 22; ++q) win[q] = xl[base + q * 64];
#pragma unroll
      for (int ky = 0; ky < 9; ++ky) {
        const float wv = wl[ci * 81 + ky * 9 + kx];
#pragma unroll
        for (int j = 0; j < 14; ++j) acc[j] = fmaf(wv, win[j + ky], acc[j]);
      }
    }
  const float bv = bias[co];
  unsigned short* hp = h_bf + (((long)b * 256 + co) * 56 + oy0) * 56 + ox;
#pragma unroll
  for (int j = 0; j < 14; ++j) {
    float v = acc[j] + bv;
    v = v > 0.f ? v : 0.f;
    hp[j * 56] = f2bf(v);
  }
}

// ---------------- prim conv implicit GEMM v2 ----------------
// C[m=4608][co=256], K=20736. grid (72 mtile, 4 ksplit), 512 thr = 8 waves (2M x 4N).
// Full-N tile: A-gather amortized over all co. Fragment-order LDS (16B unit [kgrp][row])
// -> conflict-free ds_read/ds_write. Register prefetch of next k-step.
__global__ __launch_bounds__(512) void prim_gemm(const unsigned short* __restrict__ h_bf,
                                                 const uint4* __restrict__ wbf4,
                                                 const unsigned* __restrict__ off_tab,
                                                 float* __restrict__ C_part) {
  __shared__ uint4 A4[256];    // [c:4][row:64]
  __shared__ uint4 B4[1024];   // [c:4][co:256]
  const int t = threadIdx.x;
  const int lane = t & 63, w = t >> 6;
  const int mt = blockIdx.x, kz = blockIdx.y;
  const int k0 = kz * 5184;  // 162 k-steps of 32
  const bool isA = (t < 256);
  // A-stager (t<256): row ar, k-unit ac
  const int ar = t & 63, ac = (t >> 6) & 3;
  const int m = mt * 64 + ar;
  const int b = m / 576, yx = m % 576;
  const int oy = yx / 24, ox = yx % 24;
  const long base_p = (long)b * 802816 + oy * 112 + ox * 2;
  // B-stager (t>=256): co
  const int bco = t & 255;
  // compute mapping
  const int wm = w >> 2, wn = w & 3;
  const int fr = lane & 15, fg = lane >> 4;
  f32x4 acc[2][4];
#pragma unroll
  for (int i2 = 0; i2 < 2; ++i2)
#pragma unroll
    for (int j = 0; j < 4; ++j)
#pragma unroll
      for (int e = 0; e < 4; ++e) acc[i2][j][e] = 0.f;

  union { unsigned short s[8]; uint4 v; } pa;
  uint4 pb0, pb1, pb2, pb3;
  auto loadA = [&](int kt) {
    const int kb = k0 + kt * 32 + ac * 8;
#pragma unroll
    for (int j = 0; j < 8; ++j) pa.s[j] = h_bf[base_p + off_tab[kb + j]];
  };
  auto loadB = [&](int kt) {
    const int kb0 = (k0 + kt * 32) >> 3;
    pb0 = wbf4[(kb0 + 0) * 256 + bco];
    pb1 = wbf4[(kb0 + 1) * 256 + bco];
    pb2 = wbf4[(kb0 + 2) * 256 + bco];
    pb3 = wbf4[(kb0 + 3) * 256 + bco];
  };
  if (isA) loadA(0); else loadB(0);

  const short8* A8 = (const short8*)A4;
  const short8* B8 = (const short8*)B4;
  for (int kt = 0; kt < 162; ++kt) {
    __syncthreads();  // previous step's LDS reads complete
    if (isA) {
      A4[ac * 64 + ar] = pa.v;
    } else {
      B4[bco] = pb0;
      B4[256 + bco] = pb1;
      B4[512 + bco] = pb2;
      B4[768 + bco] = pb3;
    }
    if (kt < 161) { if (isA) loadA(kt + 1); else loadB(kt + 1); }
    __syncthreads();
    const short8 a0 = A8[fg * 64 + wm * 32 + fr];
    const short8 a1 = A8[fg * 64 + wm * 32 + 16 + fr];
    const short8 b0 = B8[fg * 256 + wn * 64 + fr];
    const short8 b1 = B8[fg * 256 + wn * 64 + 16 + fr];
    const short8 b2 = B8[fg * 256 + wn * 64 + 32 + fr];
    const short8 b3 = B8[fg * 256 + wn * 64 + 48 + fr];
    acc[0][0] = __builtin_amdgcn_mfma_f32_16x16x32_bf16(a0, b0, acc[0][0], 0, 0, 0);
    acc[0][1] = __builtin_amdgcn_mfma_f32_16x16x32_bf16(a0, b1, acc[0][1], 0, 0, 0);
    acc[0][2] = __builtin_amdgcn_mfma_f32_16x16x32_bf16(a0, b2, acc[0][2], 0, 0, 0);
    acc[0][3] = __builtin_amdgcn_mfma_f32_16x16x32_bf16(a0, b3, acc[0][3], 0, 0, 0);
    acc[1][0] = __builtin_amdgcn_mfma_f32_16x16x32_bf16(a1, b0, acc[1][0], 0, 0, 0);
    acc[1][1] = __builtin_amdgcn_mfma_f32_16x16x32_bf16(a1, b1, acc[1][1], 0, 0, 0);
    acc[1][2] = __builtin_amdgcn_mfma_f32_16x16x32_bf16(a1, b2, acc[1][2], 0, 0, 0);
    acc[1][3] = __builtin_amdgcn_mfma_f32_16x16x32_bf16(a1, b3, acc[1][3], 0, 0, 0);
  }
#pragma unroll
  for (int i2 = 0; i2 < 2; ++i2)
#pragma unroll
    for (int j = 0; j < 4; ++j)
#pragma unroll
      for (int e = 0; e < 4; ++e) {
        const int row = mt * 64 + wm * 32 + i2 * 16 + fg * 4 + e;  // C row = (l>>4)*4+reg
        const int col = wn * 64 + j * 16 + fr;                     // C col = lane&15
        C_part[((long)kz * 4608 + row) * 256 + col] = acc[i2][j][e];
      }
}

// ------- combine K-split partials + bias + squash -> u fp32 + u_h f16 [8,18432,8] -------
__global__ __launch_bounds__(256) void combine_k(const float* __restrict__ C_part,
                                                 const float* __restrict__ prim_b,
                                                 float* __restrict__ u,
                                                 uint4* __restrict__ u_h) {
  const int cap = blockIdx.x * 256 + threadIdx.x;
  const int b = cap / 18432, r = cap % 18432;
  const int g = r / 576, yx = r % 576;
  const long m = (long)b * 576 + yx;
  float pv[8];
#pragma unroll
  for (int e = 0; e < 8; ++e) pv[e] = prim_b[g * 8 + e];
#pragma unroll
  for (int kz = 0; kz < 4; ++kz) {
    const float4* cp = (const float4*)(C_part + ((long)kz * 4608 + m) * 256 + g * 8);
    const float4 f0 = cp[0], f1 = cp[1];
    pv[0] += f0.x; pv[1] += f0.y; pv[2] += f0.z; pv[3] += f0.w;
    pv[4] += f1.x; pv[5] += f1.y; pv[6] += f1.z; pv[7] += f1.w;
  }
  float sn = 0.f;
#pragma unroll
  for (int e = 0; e < 8; ++e) sn += pv[e] * pv[e];
  const float f = sn / (1.f + sn) / (sqrtf(sn) + 1e-8f);
  float4 o0, o1;
  o0.x = pv[0] * f; o0.y = pv[1] * f; o0.z = pv[2] * f; o0.w = pv[3] * f;
  o1.x = pv[4] * f; o1.y = pv[5] * f; o1.z = pv[6] * f; o1.w = pv[7] * f;
  float4* up = (float4*)(u + (long)cap * 8);
  up[0] = o0; up[1] = o1;
  union { _Float16 h[8]; uint4 v; } oh;
  oh.h[0] = (_Float16)o0.x; oh.h[1] = (_Float16)o0.y; oh.h[2] = (_Float16)o0.z; oh.h[3] = (_Float16)o0.w;
  oh.h[4] = (_Float16)o1.x; oh.h[5] = (_Float16)o1.y; oh.h[6] = (_Float16)o1.z; oh.h[7] = (_Float16)o1.w;
  u_h[cap] = oh.v;
}

// ---------------- routing pass v4: f16 W + fdot2, lane = class ----------------
// 576 blocks x 512 thr (8 waves). wave = b; lane = n (50 active). Block owns 32 i.
// W rows staged via LDS (shared by 8 b-waves), chunk = 2 i, XOR-swizzled 16B slots.
// Register prefetch of next chunk. Logit dot in-thread via v_dot2_f32_f16.
// No max-subtraction (|logits| <~ 6, softmax ratio exact).
__global__ __launch_bounds__(512, 4) void route_f16(const uint4* __restrict__ Wb4,
                                                    const uint4* __restrict__ u_h,
                                                    const float* __restrict__ vsum,
                                                    float* __restrict__ S_part) {
  __shared__ uint4 lds4[1600];
  const int t = threadIdx.x;
  const int b = t >> 6, lane = t & 63;
  const bool vn = lane < 50;
  const int nr = vn ? lane : 49;
  const int nxor = nr & 15;
  const int bi = blockIdx.x;
  const int i_base = bi * 32;

  float vs[16], Sa[16];
#pragma unroll
  for (int d = 0; d < 16; ++d) {
    vs[d] = vsum[(b * 50 + nr) * 16 + d];
    Sa[d] = 0.f;
  }

  const int idx0 = t, idx1 = t + 512, idx2 = t + 1024, idx3 = t + 1536;
  const bool g2 = t < 576, g3 = t < 64;  // 1600 = 512*3 + 64
  auto gload = [&](int idx, int i0) -> uint4 {
    const int n = idx >> 5, i2 = (idx >> 4) & 1, c = idx & 15;
    return Wb4[(long)(n * 18432 + i0 + i2) * 16 + c];
  };
  auto lput = [&](int idx, uint4 v) {
    const int n = idx >> 5, i2 = (idx >> 4) & 1, c = idx & 15;
    lds4[n * 32 + i2 * 16 + (c ^ (n & 15))] = v;
  };
  uint4 r0, r1, r2, r3;
  const uint4 zz = make_uint4(0, 0, 0, 0);
  r0 = gload(idx0, i_base);
  r1 = gload(idx1, i_base);
  r2 = g2 ? gload(idx2, i_base) : zz;
  r3 = g3 ? gload(idx3, i_base) : zz;

  for (int ch = 0; ch < 16; ++ch) {
    __syncthreads();  // previous chunk's LDS reads complete
    lput(idx0, r0);
    lput(idx1, r1);
    if (g2) lput(idx2, r2);
    if (g3) lput(idx3, r3);
    if (ch < 15) {  // issue next chunk's global loads; latency hides under compute
      const int ni = i_base + (ch + 1) * 2;
      r0 = gload(idx0, ni);
      r1 = gload(idx1, ni);
      if (g2) r2 = gload(idx2, ni);
      if (g3) r3 = gload(idx3, ni);
    }
    __syncthreads();
#pragma unroll
    for (int ii = 0; ii < 2; ++ii) {
      const int i = i_base + ch * 2 + ii;
      const uint4 uv = u_h[(long)b * 18432 + i];
      const h2 ua0 = u2h2(uv.x), ua1 = u2h2(uv.y), ua2 = u2h2(uv.z), ua3 = u2h2(uv.w);
      const uint4* lrow = &lds4[nr * 32 + ii * 16];
      float uh[16];
      float lg = 0.f;
#pragma unroll
      for (int d = 0; d < 16; ++d) {
        const uint4 wv = lrow[d ^ nxor];
        float a = FDOT2(u2h2(wv.x), ua0, 0.f);
        a = FDOT2(u2h2(wv.y), ua1, a);
        a = FDOT2(u2h2(wv.z), ua2, a);
        a = FDOT2(u2h2(wv.w), ua3, a);
        uh[d] = a;
        lg = fmaf(a, vs[d], lg);
      }
      float p = vn ? __expf(lg) : 0.f;
      float sm = p;
      sm += __shfl_xor(sm, 1);
      sm += __shfl_xor(sm, 2);
      sm += __shfl_xor(sm, 4);
      sm += __shfl_xor(sm, 8);
      sm += __shfl_xor(sm, 16);
      sm += __shfl_xor(sm, 32);
      const float sc = p / sm;
#pragma unroll
      for (int d = 0; d < 16; ++d) Sa[d] = fmaf(sc, uh[d], Sa[d]);
    }
  }
  if (vn) {
    float* Sp = S_part + (long)bi * 6400 + b * 800 + lane * 16;
#pragma unroll
    for (int d = 0; d < 16; ++d) Sp[d] = Sa[d];
  }
}

// ---------------- routing pass (fp32 fallback, proven) ----------------
__global__ __launch_bounds__(512, 4) void route_pass_f32(const float* __restrict__ W,
                                                         const float* __restrict__ u,
                                                         const float* __restrict__ vsum,
                                                         float* __restrict__ S_part) {
  const int t = threadIdx.x;
  const int b = t >> 6;
  const int lane = t & 63;
  const int d = lane & 15, nq = lane >> 4;
  const int qmax = (nq == 3) ? 11 : 13;
  int nn[13];
  float vs[13], Sa[13], uh[13], lg[13];
#pragma unroll
  for (int q = 0; q < 13; ++q) {
    const int n = nq * 13 + q;
    const bool valid = n < 50;
    nn[q] = valid ? n : 49;
    vs[q] = valid ? vsum[(b * 50 + n) * 16 + d] : 0.f;
    Sa[q] = 0.f;
  }
  const int bi = blockIdx.x;
  for (int ii = 0; ii < 32; ++ii) {
    const int i = bi * 32 + ii;
    const float4* up = (const float4*)(u + ((long)b * 18432 + i) * 8);
    const float4 u0 = up[0], u1 = up[1];
    const float* Wi = W + (long)i * 128 + d * 8;
#pragma unroll
    for (int q = 0; q < 13; ++q) {
      const float4* wp = (const float4*)(Wi + (long)nn[q] * 2359296);
      const float4 w0 = wp[0], w1 = wp[1];
      const float s = w0.x * u0.x + w0.y * u0.y + w0.z * u0.z + w0.w * u0.w +
                      w1.x * u1.x + w1.y * u1.y + w1.z * u1.z + w1.w * u1.w;
      uh[q] = s;
      float v = s * vs[q];
      v += __shfl_xor(v, 1);
      v += __shfl_xor(v, 2);
      v += __shfl_xor(v, 4);
      v += __shfl_xor(v, 8);
      lg[q] = (q < qmax) ? v : -1e30f;
    }
    float mx = lg[0];
#pragma unroll
    for (int q = 1; q < 13; ++q) mx = fmaxf(mx, lg[q]);
    mx = fmaxf(mx, __shfl_xor(mx, 16));
    mx = fmaxf(mx, __shfl_xor(mx, 32));
    float sm = 0.f;
#pragma unroll
    for (int q = 0; q < 13; ++q) {
      const float e = __expf(lg[q] - mx);
      lg[q] = e;
      sm += e;
    }
    sm += __shfl_xor(sm, 16);
    sm += __shfl_xor(sm, 32);
    const float inv = 1.f / sm;
#pragma unroll
    for (int q = 0; q < 13; ++q) Sa[q] = fmaf(lg[q] * inv, uh[q], Sa[q]);
  }
  float* Sp = S_part + ((long)bi * 8 + b) * 800;
#pragma unroll
  for (int q = 0; q < 13; ++q)
    if (q < qmax) Sp[(nq * 13 + q) * 16 + d] = Sa[q];
}

// ---------------- reduce 576 partials -> v = squash(S); vsum += v or v3 = v ------
__global__ __launch_bounds__(256) void route_reduce(const float* __restrict__ S_part,
                                                    float* __restrict__ vsum,
                                                    float* __restrict__ v3,
                                                    const int pass) {
  __shared__ float lds[256];
  const int bn = blockIdx.x;  // 400 = b*50+n
  const int b = bn / 50, n = bn % 50;
  const int t = threadIdx.x;
  const int kk = t >> 4, dd = t & 15;
  float s = 0.f;
  const float* p = S_part + (long)b * 800 + n * 16 + dd;
  for (int j = kk; j < 576; j += 16) s += p[(long)j * 6400];
  lds[t] = s;
  __syncthreads();
  for (int off = 128; off >= 16; off >>= 1) {
    if (t < off) lds[t] += lds[t + off];
    __syncthreads();
  }
  if (t < 16) {
    const float S = lds[t];
    float sq = S * S;
    sq += __shfl_xor(sq, 1);
    sq += __shfl_xor(sq, 2);
    sq += __shfl_xor(sq, 4);
    sq += __shfl_xor(sq, 8);
    const float f = sq / (1.f + sq) / (sqrtf(sq) + 1e-8f);
    const float v = S * f;
    const int o = bn * 16 + t;
    if (pass < 3) vsum[o] += v;
    else v3[o] = v;
  }
}

// ---------------- preds, argmax, select masked capsule ----------------
__global__ __launch_bounds__(512) void head_k(const float* __restrict__ v3,
                                              float* __restrict__ out,
                                              float* __restrict__ selv,
                                              int* __restrict__ idxs) {
  __shared__ float pl[400];
  const int t = threadIdx.x;
  if (t < 400) {
    const float4* vp = (const float4*)(v3 + t * 16);
    const float4 a = vp[0], b = vp[1], c = vp[2], d = vp[3];
    const float s = a.x * a.x + a.y * a.y + a.z * a.z + a.w * a.w +
                    b.x * b.x + b.y * b.y + b.z * b.z + b.w * b.w +
                    c.x * c.x + c.y * c.y + c.z * c.z + c.w * c.w +
                    d.x * d.x + d.y * d.y + d.z * d.z + d.w * d.w;
    const float p = sqrtf(s);
    out[t] = p;
    pl[t] = p;
  }
  __syncthreads();
  if (t < 8) {
    float best = -1e30f;
    int bi = 0;
    for (int n = 0; n < 50; ++n) {
      const float p = pl[t * 50 + n];
      if (p > best) { best = p; bi = n; }
    }
    idxs[t] = bi;
    for (int k = 0; k < 16; ++k) selv[t * 16 + k] = v3[(t * 50 + bi) * 16 + k];
  }
}

// ---------------- decoder ----------------
__global__ __launch_bounds__(512) void d1_k(const float* __restrict__ selv,
                                            const int* __restrict__ idxs,
                                            const float* __restrict__ d1w,
                                            const float* __restrict__ d1b,
                                            float* __restrict__ r1) {
  const int b = blockIdx.x, j = threadIdx.x;
  const int idx = idxs[b];
  const float* wr = d1w + j * 800 + idx * 16;
  float acc = d1b[j];
#pragma unroll
  for (int k = 0; k < 16; ++k) acc = fmaf(selv[b * 16 + k], wr[k], acc);
  r1[b * 512 + j] = acc > 0.f ? acc : 0.f;
}

__global__ __launch_bounds__(256) void d2_k(const float* __restrict__ r1,
                                            const float* __restrict__ d2w,
                                            const float* __restrict__ d2b,
                                            float* __restrict__ r2) {
  __shared__ float rl[512];
  const int b = blockIdx.y;
  const int j = blockIdx.x * 256 + threadIdx.x;
  for (int r = threadIdx.x; r < 512; r += 256) rl[r] = r1[b * 512 + r];
  __syncthreads();
  const float4* wr = (const float4*)(d2w + (long)j * 512);
  float acc = d2b[j];
  for (int k4 = 0; k4 < 128; ++k4) {
    const float4 w = wr[k4];
    acc += w.x * rl[k4 * 4] + w.y * rl[k4 * 4 + 1] + w.z * rl[k4 * 4 + 2] + w.w * rl[k4 * 4 + 3];
  }
  r2[b * 1024 + j] = acc > 0.f ? acc : 0.f;
}

__global__ __launch_bounds__(256) void d3_k(const float* __restrict__ r2,
                                            const float* __restrict__ d3w,
                                            const float* __restrict__ d3b,
                                            float* __restrict__ out) {
  __shared__ float rl[8192];
  const int j = blockIdx.x * 256 + threadIdx.x;
  float4* rl4 = (float4*)rl;
  for (int r = threadIdx.x; r < 2048; r += 256) rl4[r] = ((const float4*)r2)[r];
  __syncthreads();
  float acc[8];
  const float bv = d3b[j];
#pragma unroll
  for (int b = 0; b < 8; ++b) acc[b] = bv;
  const float4* wr = (const float4*)d3w + (long)j * 256;
  for (int k4 = 0; k4 < 256; ++k4) {
    const float4 w = wr[k4];
#pragma unroll
    for (int b = 0; b < 8; ++b) {
      const int o = b * 1024 + k4 * 4;
      acc[b] += w.x * rl[o] + w.y * rl[o + 1] + w.z * rl[o + 2] + w.w * rl[o + 3];
    }
  }
#pragma unroll
  for (int b = 0; b < 8; ++b)
    out[400 + b * 12288 + j] = 1.f / (1.f + __expf(-acc[b]));
}

extern "C" void kernel_launch(void* const* d_in, const int* in_sizes, int n_in,
                              void* d_out, int out_size, void* d_ws, size_t ws_size,
                              hipStream_t stream) {
  const float* x   = (const float*)d_in[0];
  const float* c1w = (const float*)d_in[1];
  const float* c1b = (const float*)d_in[2];
  const float* pw  = (const float*)d_in[3];
  const float* pb  = (const float*)d_in[4];
  const float* W   = (const float*)d_in[5];
  const float* d1w = (const float*)d_in[6];
  const float* d1b = (const float*)d_in[7];
  const float* d2w = (const float*)d_in[8];
  const float* d2b = (const float*)d_in[9];
  const float* d3w = (const float*)d_in[10];
  const float* d3b = (const float*)d_in[11];
  float* out = (float*)d_out;

  char* wsb = (char*)d_ws;
  size_t off = 0;
  auto alloc = [&](size_t bytes) -> char* {
    char* p = wsb + off;
    off += (bytes + 255) & ~(size_t)255;
    return p;
  };
  unsigned short* h_bf   = (unsigned short*)alloc(12845056);  // bf16 h
  unsigned short* wbf    = (unsigned short*)alloc(10616832);  // bf16 tiled prim_w
  unsigned*       offt   = (unsigned*)alloc(82944);
  // C_part (18.9 MB) and S_part (14.75 MB) alias (disjoint lifetimes).
  char*           bigA   = alloc(18874368);
  float*          C_part = (float*)bigA;
  float*          S_part = (float*)bigA;
  float*          u      = (float*)alloc(4718592);
  uint4*          u_h    = (uint4*)alloc(2359296);   // f16 u
  float*          vsum   = (float*)alloc(25600);
  float*          v3     = (float*)alloc(25600);
  float*          selv   = (float*)alloc(512);
  int*            idxs   = (int*)alloc(64);
  float*          r1     = (float*)alloc(16384);
  float*          r2     = (float*)alloc(32768);
  const size_t off_base = off;
  uint4*          Whf    = (uint4*)alloc(235929600);  // f16 routing W
  const bool f16_route = (off <= ws_size);
  if (off_base > ws_size) return;  // even fallback doesn't fit: outputs stay poisoned

  offtab_k<<<81, 256, 0, stream>>>(offt);
  wconv_k<<<2592, 256, 0, stream>>>(pw, wbf);
  conv1_k<<<2048, 256, 0, stream>>>(x, c1w, c1b, h_bf);
  prim_gemm<<<dim3(72, 4), 512, 0, stream>>>(h_bf, (const uint4*)wbf, offt, C_part);
  combine_k<<<576, 256, 0, stream>>>(C_part, pb, u, u_h);
  if (f16_route) wcvt_k<<<28800, 512, 0, stream>>>(W, Whf);
  hipMemsetAsync(vsum, 0, 25600, stream);
  for (int pass = 1; pass <= 3; ++pass) {
    if (f16_route)
      route_f16<<<576, 512, 0, stream>>>(Whf, u_h, vsum, S_part);
    else
      route_pass_f32<<<576, 512, 0, stream>>>(W, u, vsum, S_part);
    route_reduce<<<400, 256, 0, stream>>>(S_part, vsum, v3, pass);
  }
  head_k<<<1, 512, 0, stream>>>(v3, out, selv, idxs);
  d1_k<<<8, 512, 0, stream>>>(selv, idxs, d1w, d1b, r1);
  d2_k<<<dim3(4, 8), 256, 0, stream>>>(r1, d2w, d2b, r2);
  d3_k<<<48, 256, 0, stream>>>(r2, d3w, d3b, out);
}

// Round 5
// 765.182 us; speedup vs baseline: 3.9317x; 1.0080x over previous
//
#include <hip/hip_runtime.h>

typedef short short8 __attribute__((ext_vector_type(8)));
typedef float f32x4 __attribute__((ext_vector_type(4)));
typedef _Float16 h2 __attribute__((ext_vector_type(2)));

__device__ __forceinline__ unsigned short f2bf(float f) {
  union { float f; unsigned u; } a; a.f = f;
  unsigned r = a.u + 0x7fffu + ((a.u >> 16) & 1u);
  return (unsigned short)(r >> 16);
}

__device__ __forceinline__ h2 u2h2(unsigned w) {
  union { unsigned u; h2 h; } q; q.u = w; return q.h;
}

#if __has_builtin(__builtin_amdgcn_fdot2)
#define FDOT2(a, b, c) __builtin_amdgcn_fdot2((a), (b), (c), false)
#else
#define FDOT2(a, b, c) ((c) + (float)(a)[0] * (float)(b)[0] + (float)(a)[1] * (float)(b)[1])
#endif

// ---------------- tap offset table: off[k] = ci*3136 + ky*56 + kx ----------------
__global__ void offtab_k(unsigned* __restrict__ off_tab) {
  const int k = blockIdx.x * 256 + threadIdx.x;  // 81*256 = 20736 exact
  const int ci = k / 81, rr = k % 81;
  const int ky = rr / 9, kx = rr % 9;
  off_tab[k] = (unsigned)(ci * 3136 + ky * 56 + kx);
}

// ---------------- prim_w fp32 -> bf16 tiled [kb][co][8] ----------------
__global__ __launch_bounds__(256) void wconv_k(const float* __restrict__ pw,
                                               unsigned short* __restrict__ wbf) {
  const int kb = blockIdx.x, co = threadIdx.x;  // 2592 blocks
  const float4* src = (const float4*)(pw + (long)co * 20736 + kb * 8);
  const float4 a = src[0], b = src[1];
  union { unsigned short s[8]; short8 v; } o;
  o.s[0] = f2bf(a.x); o.s[1] = f2bf(a.y); o.s[2] = f2bf(a.z); o.s[3] = f2bf(a.w);
  o.s[4] = f2bf(b.x); o.s[5] = f2bf(b.y); o.s[6] = f2bf(b.z); o.s[7] = f2bf(b.w);
  *reinterpret_cast<short8*>(&wbf[((long)kb * 256 + co) * 8]) = o.v;
}

// ---------------- routing W fp32 -> f16 (same [n][i][d][e] layout) ----------------
__global__ __launch_bounds__(512) void wcvt_k(const float* __restrict__ W,
                                              uint4* __restrict__ Wh) {
  const long unit = (long)blockIdx.x * 512 + threadIdx.x;  // 28800*512 = 14,745,600 exact
  const float4* src = (const float4*)(W + unit * 8);
  const float4 a = src[0], b = src[1];
  union { _Float16 h[8]; uint4 v; } o;
  o.h[0] = (_Float16)a.x; o.h[1] = (_Float16)a.y; o.h[2] = (_Float16)a.z; o.h[3] = (_Float16)a.w;
  o.h[4] = (_Float16)b.x; o.h[5] = (_Float16)b.y; o.h[6] = (_Float16)b.z; o.h[7] = (_Float16)b.w;
  Wh[unit] = o.v;
}

// ---------------- conv1: [8,3,64,64] -> bf16 h [8,256,56,56], relu ----------------
__global__ __launch_bounds__(256) void conv1_k(const float* __restrict__ x,
                                               const float* __restrict__ w,
                                               const float* __restrict__ bias,
                                               unsigned short* __restrict__ h_bf) {
  __shared__ float xl[12288];
  __shared__ float wl[244];
  const int blk = blockIdx.x;          // 2048 = 8b * 256co
  const int b = blk >> 8, co = blk & 255;
  const int t = threadIdx.x;
  const float4* xb = (const float4*)(x + b * 12288);
  float4* xl4 = (float4*)xl;
  for (int r = t; r < 3072; r += 256) xl4[r] = xb[r];
  for (int r = t; r < 243; r += 256) wl[r] = w[co * 243 + r];
  __syncthreads();
  if (t >= 224) return;
  const int ox = t % 56, oy0 = (t / 56) * 14;
  float acc[14];
#pragma unroll
  for (int j = 0; j < 14; ++j) acc[j] = 0.f;
  for (int ci = 0; ci < 3; ++ci)
    for (int kx = 0; kx < 9; ++kx) {
      const int base = ci * 4096 + oy0 * 64 + ox + kx;
      float win[22];
#pragma unroll
      for (int q = 0; q < 22; ++q) win[q] = xl[base + q * 64];
#pragma unroll
      for (int ky = 0; ky < 9; ++ky) {
        const float wv = wl[ci * 81 + ky * 9 + kx];
#pragma unroll
        for (int j = 0; j < 14; ++j) acc[j] = fmaf(wv, win[j + ky], acc[j]);
      }
    }
  const float bv = bias[co];
  unsigned short* hp = h_bf + (((long)b * 256 + co) * 56 + oy0) * 56 + ox;
#pragma unroll
  for (int j = 0; j < 14; ++j) {
    float v = acc[j] + bv;
    v = v > 0.f ? v : 0.f;
    hp[j * 56] = f2bf(v);
  }
}

// ---------------- prim conv implicit GEMM v2 ----------------
// C[m=4608][co=256], K=20736. grid (72 mtile, 4 ksplit), 512 thr = 8 waves (2M x 4N).
__global__ __launch_bounds__(512) void prim_gemm(const unsigned short* __restrict__ h_bf,
                                                 const uint4* __restrict__ wbf4,
                                                 const unsigned* __restrict__ off_tab,
                                                 float* __restrict__ C_part) {
  __shared__ uint4 A4[256];    // [c:4][row:64]
  __shared__ uint4 B4[1024];   // [c:4][co:256]
  const int t = threadIdx.x;
  const int lane = t & 63, w = t >> 6;
  const int mt = blockIdx.x, kz = blockIdx.y;
  const int k0 = kz * 5184;  // 162 k-steps of 32
  const bool isA = (t < 256);
  const int ar = t & 63, ac = (t >> 6) & 3;
  const int m = mt * 64 + ar;
  const int b = m / 576, yx = m % 576;
  const int oy = yx / 24, ox = yx % 24;
  const long base_p = (long)b * 802816 + oy * 112 + ox * 2;
  const int bco = t & 255;
  const int wm = w >> 2, wn = w & 3;
  const int fr = lane & 15, fg = lane >> 4;
  f32x4 acc[2][4];
#pragma unroll
  for (int i2 = 0; i2 < 2; ++i2)
#pragma unroll
    for (int j = 0; j < 4; ++j)
#pragma unroll
      for (int e = 0; e < 4; ++e) acc[i2][j][e] = 0.f;

  union { unsigned short s[8]; uint4 v; } pa;
  uint4 pb0, pb1, pb2, pb3;
  auto loadA = [&](int kt) {
    const int kb = k0 + kt * 32 + ac * 8;
#pragma unroll
    for (int j = 0; j < 8; ++j) pa.s[j] = h_bf[base_p + off_tab[kb + j]];
  };
  auto loadB = [&](int kt) {
    const int kb0 = (k0 + kt * 32) >> 3;
    pb0 = wbf4[(kb0 + 0) * 256 + bco];
    pb1 = wbf4[(kb0 + 1) * 256 + bco];
    pb2 = wbf4[(kb0 + 2) * 256 + bco];
    pb3 = wbf4[(kb0 + 3) * 256 + bco];
  };
  if (isA) loadA(0); else loadB(0);

  const short8* A8 = (const short8*)A4;
  const short8* B8 = (const short8*)B4;
  for (int kt = 0; kt < 162; ++kt) {
    __syncthreads();
    if (isA) {
      A4[ac * 64 + ar] = pa.v;
    } else {
      B4[bco] = pb0;
      B4[256 + bco] = pb1;
      B4[512 + bco] = pb2;
      B4[768 + bco] = pb3;
    }
    if (kt < 161) { if (isA) loadA(kt + 1); else loadB(kt + 1); }
    __syncthreads();
    const short8 a0 = A8[fg * 64 + wm * 32 + fr];
    const short8 a1 = A8[fg * 64 + wm * 32 + 16 + fr];
    const short8 b0 = B8[fg * 256 + wn * 64 + fr];
    const short8 b1 = B8[fg * 256 + wn * 64 + 16 + fr];
    const short8 b2 = B8[fg * 256 + wn * 64 + 32 + fr];
    const short8 b3 = B8[fg * 256 + wn * 64 + 48 + fr];
    acc[0][0] = __builtin_amdgcn_mfma_f32_16x16x32_bf16(a0, b0, acc[0][0], 0, 0, 0);
    acc[0][1] = __builtin_amdgcn_mfma_f32_16x16x32_bf16(a0, b1, acc[0][1], 0, 0, 0);
    acc[0][2] = __builtin_amdgcn_mfma_f32_16x16x32_bf16(a0, b2, acc[0][2], 0, 0, 0);
    acc[0][3] = __builtin_amdgcn_mfma_f32_16x16x32_bf16(a0, b3, acc[0][3], 0, 0, 0);
    acc[1][0] = __builtin_amdgcn_mfma_f32_16x16x32_bf16(a1, b0, acc[1][0], 0, 0, 0);
    acc[1][1] = __builtin_amdgcn_mfma_f32_16x16x32_bf16(a1, b1, acc[1][1], 0, 0, 0);
    acc[1][2] = __builtin_amdgcn_mfma_f32_16x16x32_bf16(a1, b2, acc[1][2], 0, 0, 0);
    acc[1][3] = __builtin_amdgcn_mfma_f32_16x16x32_bf16(a1, b3, acc[1][3], 0, 0, 0);
  }
#pragma unroll
  for (int i2 = 0; i2 < 2; ++i2)
#pragma unroll
    for (int j = 0; j < 4; ++j)
#pragma unroll
      for (int e = 0; e < 4; ++e) {
        const int row = mt * 64 + wm * 32 + i2 * 16 + fg * 4 + e;
        const int col = wn * 64 + j * 16 + fr;
        C_part[((long)kz * 4608 + row) * 256 + col] = acc[i2][j][e];
      }
}

// ------- combine K-split partials + bias + squash -> u fp32 + u_h f16 [8,18432,8] -------
__global__ __launch_bounds__(256) void combine_k(const float* __restrict__ C_part,
                                                 const float* __restrict__ prim_b,
                                                 float* __restrict__ u,
                                                 uint4* __restrict__ u_h) {
  const int cap = blockIdx.x * 256 + threadIdx.x;
  const int b = cap / 18432, r = cap % 18432;
  const int g = r / 576, yx = r % 576;
  const long m = (long)b * 576 + yx;
  float pv[8];
#pragma unroll
  for (int e = 0; e < 8; ++e) pv[e] = prim_b[g * 8 + e];
#pragma unroll
  for (int kz = 0; kz < 4; ++kz) {
    const float4* cp = (const float4*)(C_part + ((long)kz * 4608 + m) * 256 + g * 8);
    const float4 f0 = cp[0], f1 = cp[1];
    pv[0] += f0.x; pv[1] += f0.y; pv[2] += f0.z; pv[3] += f0.w;
    pv[4] += f1.x; pv[5] += f1.y; pv[6] += f1.z; pv[7] += f1.w;
  }
  float sn = 0.f;
#pragma unroll
  for (int e = 0; e < 8; ++e) sn += pv[e] * pv[e];
  const float f = sn / (1.f + sn) / (sqrtf(sn) + 1e-8f);
  float4 o0, o1;
  o0.x = pv[0] * f; o0.y = pv[1] * f; o0.z = pv[2] * f; o0.w = pv[3] * f;
  o1.x = pv[4] * f; o1.y = pv[5] * f; o1.z = pv[6] * f; o1.w = pv[7] * f;
  float4* up = (float4*)(u + (long)cap * 8);
  up[0] = o0; up[1] = o1;
  union { _Float16 h[8]; uint4 v; } oh;
  oh.h[0] = (_Float16)o0.x; oh.h[1] = (_Float16)o0.y; oh.h[2] = (_Float16)o0.z; oh.h[3] = (_Float16)o0.w;
  oh.h[4] = (_Float16)o1.x; oh.h[5] = (_Float16)o1.y; oh.h[6] = (_Float16)o1.z; oh.h[7] = (_Float16)o1.w;
  u_h[cap] = oh.v;
}

// ---------------- routing pass v5: f16 W + fdot2, lane = class, 2 batches/wave ----------------
// 576 blocks x 256 thr (4 waves). wave w -> b = {2w, 2w+1}; lane = n (50 active).
// Block owns 32 i. W staged via LDS chunks of 2 i (1600 x 16B, XOR-swizzled);
// each thread reads a W unit ONCE and dots it against both batches' u -> LDS
// traffic halved vs 8-wave version. Register prefetch of next chunk.
// No max-subtraction (|logits| small; softmax ratio exact).
__global__ __launch_bounds__(256) void route_f16(const uint4* __restrict__ Wb4,
                                                 const uint4* __restrict__ u_h,
                                                 const float* __restrict__ vsum,
                                                 float* __restrict__ S_part) {
  __shared__ uint4 lds4[1600];
  const int t = threadIdx.x;
  const int w = t >> 6, lane = t & 63;
  const int b0 = 2 * w, b1 = 2 * w + 1;
  const bool vn = lane < 50;
  const int nr = vn ? lane : 49;
  const int nxor = nr & 15;
  const int bi = blockIdx.x;
  const int i_base = bi * 32;

  float vs0[16], vs1[16], Sa0[16], Sa1[16];
#pragma unroll
  for (int d = 0; d < 16; ++d) {
    vs0[d] = vsum[(b0 * 50 + nr) * 16 + d];
    vs1[d] = vsum[(b1 * 50 + nr) * 16 + d];
    Sa0[d] = 0.f;
    Sa1[d] = 0.f;
  }

  auto gload = [&](int idx, int i0) -> uint4 {
    const int n = idx >> 5, i2 = (idx >> 4) & 1, c = idx & 15;
    return Wb4[(long)(n * 18432 + i0 + i2) * 16 + c];
  };
  auto lput = [&](int idx, uint4 v) {
    const int n = idx >> 5, i2 = (idx >> 4) & 1, c = idx & 15;
    lds4[n * 32 + i2 * 16 + (c ^ (n & 15))] = v;
  };
  // 1600 units / 256 threads: slots t+256k for k=0..5, plus t+1536 for t<64.
  const bool g6 = t < 64;
  uint4 r[7];
  const uint4 zz = make_uint4(0, 0, 0, 0);
#pragma unroll
  for (int k = 0; k < 6; ++k) r[k] = gload(t + 256 * k, i_base);
  r[6] = g6 ? gload(t + 1536, i_base) : zz;

  for (int ch = 0; ch < 16; ++ch) {
    __syncthreads();  // previous chunk's LDS reads complete
#pragma unroll
    for (int k = 0; k < 6; ++k) lput(t + 256 * k, r[k]);
    if (g6) lput(t + 1536, r[6]);
    if (ch < 15) {  // prefetch next chunk; latency hides under compute
      const int ni = i_base + (ch + 1) * 2;
#pragma unroll
      for (int k = 0; k < 6; ++k) r[k] = gload(t + 256 * k, ni);
      if (g6) r[6] = gload(t + 1536, ni);
    }
    __syncthreads();
#pragma unroll
    for (int ii = 0; ii < 2; ++ii) {
      const int i = i_base + ch * 2 + ii;
      const uint4 uv0 = u_h[(long)b0 * 18432 + i];
      const uint4 uv1 = u_h[(long)b1 * 18432 + i];
      const h2 a00 = u2h2(uv0.x), a01 = u2h2(uv0.y), a02 = u2h2(uv0.z), a03 = u2h2(uv0.w);
      const h2 a10 = u2h2(uv1.x), a11 = u2h2(uv1.y), a12 = u2h2(uv1.z), a13 = u2h2(uv1.w);
      const uint4* lrow = &lds4[nr * 32 + ii * 16];
      float uh0[16], uh1[16];
      float lg0 = 0.f, lg1 = 0.f;
#pragma unroll
      for (int d = 0; d < 16; ++d) {
        const uint4 wv = lrow[d ^ nxor];
        const h2 w0 = u2h2(wv.x), w1 = u2h2(wv.y), w2 = u2h2(wv.z), w3 = u2h2(wv.w);
        float s0 = FDOT2(w0, a00, 0.f);
        s0 = FDOT2(w1, a01, s0);
        s0 = FDOT2(w2, a02, s0);
        s0 = FDOT2(w3, a03, s0);
        uh0[d] = s0;
        lg0 = fmaf(s0, vs0[d], lg0);
        float s1 = FDOT2(w0, a10, 0.f);
        s1 = FDOT2(w1, a11, s1);
        s1 = FDOT2(w2, a12, s1);
        s1 = FDOT2(w3, a13, s1);
        uh1[d] = s1;
        lg1 = fmaf(s1, vs1[d], lg1);
      }
      float p0 = vn ? __expf(lg0) : 0.f;
      float p1 = vn ? __expf(lg1) : 0.f;
      float sm0 = p0, sm1 = p1;
      sm0 += __shfl_xor(sm0, 1);
      sm1 += __shfl_xor(sm1, 1);
      sm0 += __shfl_xor(sm0, 2);
      sm1 += __shfl_xor(sm1, 2);
      sm0 += __shfl_xor(sm0, 4);
      sm1 += __shfl_xor(sm1, 4);
      sm0 += __shfl_xor(sm0, 8);
      sm1 += __shfl_xor(sm1, 8);
      sm0 += __shfl_xor(sm0, 16);
      sm1 += __shfl_xor(sm1, 16);
      sm0 += __shfl_xor(sm0, 32);
      sm1 += __shfl_xor(sm1, 32);
      const float sc0 = p0 / sm0;
      const float sc1 = p1 / sm1;
#pragma unroll
      for (int d = 0; d < 16; ++d) {
        Sa0[d] = fmaf(sc0, uh0[d], Sa0[d]);
        Sa1[d] = fmaf(sc1, uh1[d], Sa1[d]);
      }
    }
  }
  if (vn) {
    float* Sp0 = S_part + (long)bi * 6400 + b0 * 800 + lane * 16;
    float* Sp1 = S_part + (long)bi * 6400 + b1 * 800 + lane * 16;
#pragma unroll
    for (int d = 0; d < 16; ++d) {
      Sp0[d] = Sa0[d];
      Sp1[d] = Sa1[d];
    }
  }
}

// ---------------- routing pass (fp32 fallback, proven) ----------------
__global__ __launch_bounds__(512, 4) void route_pass_f32(const float* __restrict__ W,
                                                         const float* __restrict__ u,
                                                         const float* __restrict__ vsum,
                                                         float* __restrict__ S_part) {
  const int t = threadIdx.x;
  const int b = t >> 6;
  const int lane = t & 63;
  const int d = lane & 15, nq = lane >> 4;
  const int qmax = (nq == 3) ? 11 : 13;
  int nn[13];
  float vs[13], Sa[13], uh[13], lg[13];
#pragma unroll
  for (int q = 0; q < 13; ++q) {
    const int n = nq * 13 + q;
    const bool valid = n < 50;
    nn[q] = valid ? n : 49;
    vs[q] = valid ? vsum[(b * 50 + n) * 16 + d] : 0.f;
    Sa[q] = 0.f;
  }
  const int bi = blockIdx.x;
  for (int ii = 0; ii < 32; ++ii) {
    const int i = bi * 32 + ii;
    const float4* up = (const float4*)(u + ((long)b * 18432 + i) * 8);
    const float4 u0 = up[0], u1 = up[1];
    const float* Wi = W + (long)i * 128 + d * 8;
#pragma unroll
    for (int q = 0; q < 13; ++q) {
      const float4* wp = (const float4*)(Wi + (long)nn[q] * 2359296);
      const float4 w0 = wp[0], w1 = wp[1];
      const float s = w0.x * u0.x + w0.y * u0.y + w0.z * u0.z + w0.w * u0.w +
                      w1.x * u1.x + w1.y * u1.y + w1.z * u1.z + w1.w * u1.w;
      uh[q] = s;
      float v = s * vs[q];
      v += __shfl_xor(v, 1);
      v += __shfl_xor(v, 2);
      v += __shfl_xor(v, 4);
      v += __shfl_xor(v, 8);
      lg[q] = (q < qmax) ? v : -1e30f;
    }
    float mx = lg[0];
#pragma unroll
    for (int q = 1; q < 13; ++q) mx = fmaxf(mx, lg[q]);
    mx = fmaxf(mx, __shfl_xor(mx, 16));
    mx = fmaxf(mx, __shfl_xor(mx, 32));
    float sm = 0.f;
#pragma unroll
    for (int q = 0; q < 13; ++q) {
      const float e = __expf(lg[q] - mx);
      lg[q] = e;
      sm += e;
    }
    sm += __shfl_xor(sm, 16);
    sm += __shfl_xor(sm, 32);
    const float inv = 1.f / sm;
#pragma unroll
    for (int q = 0; q < 13; ++q) Sa[q] = fmaf(lg[q] * inv, uh[q], Sa[q]);
  }
  float* Sp = S_part + ((long)bi * 8 + b) * 800;
#pragma unroll
  for (int q = 0; q < 13; ++q)
    if (q < qmax) Sp[(nq * 13 + q) * 16 + d] = Sa[q];
}

// ---------------- reduce 576 partials -> v = squash(S); vsum += v or v3 = v ------
__global__ __launch_bounds__(256) void route_reduce(const float* __restrict__ S_part,
                                                    float* __restrict__ vsum,
                                                    float* __restrict__ v3,
                                                    const int pass) {
  __shared__ float lds[256];
  const int bn = blockIdx.x;  // 400 = b*50+n
  const int b = bn / 50, n = bn % 50;
  const int t = threadIdx.x;
  const int kk = t >> 4, dd = t & 15;
  float s = 0.f;
  const float* p = S_part + (long)b * 800 + n * 16 + dd;
  for (int j = kk; j < 576; j += 16) s += p[(long)j * 6400];
  lds[t] = s;
  __syncthreads();
  for (int off = 128; off >= 16; off >>= 1) {
    if (t < off) lds[t] += lds[t + off];
    __syncthreads();
  }
  if (t < 16) {
    const float S = lds[t];
    float sq = S * S;
    sq += __shfl_xor(sq, 1);
    sq += __shfl_xor(sq, 2);
    sq += __shfl_xor(sq, 4);
    sq += __shfl_xor(sq, 8);
    const float f = sq / (1.f + sq) / (sqrtf(sq) + 1e-8f);
    const float v = S * f;
    const int o = bn * 16 + t;
    if (pass < 3) vsum[o] += v;
    else v3[o] = v;
  }
}

// ---------------- preds, argmax, select masked capsule ----------------
__global__ __launch_bounds__(512) void head_k(const float* __restrict__ v3,
                                              float* __restrict__ out,
                                              float* __restrict__ selv,
                                              int* __restrict__ idxs) {
  __shared__ float pl[400];
  const int t = threadIdx.x;
  if (t < 400) {
    const float4* vp = (const float4*)(v3 + t * 16);
    const float4 a = vp[0], b = vp[1], c = vp[2], d = vp[3];
    const float s = a.x * a.x + a.y * a.y + a.z * a.z + a.w * a.w +
                    b.x * b.x + b.y * b.y + b.z * b.z + b.w * b.w +
                    c.x * c.x + c.y * c.y + c.z * c.z + c.w * c.w +
                    d.x * d.x + d.y * d.y + d.z * d.z + d.w * d.w;
    const float p = sqrtf(s);
    out[t] = p;
    pl[t] = p;
  }
  __syncthreads();
  if (t < 8) {
    float best = -1e30f;
    int bi = 0;
    for (int n = 0; n < 50; ++n) {
      const float p = pl[t * 50 + n];
      if (p > best) { best = p; bi = n; }
    }
    idxs[t] = bi;
    for (int k = 0; k < 16; ++k) selv[t * 16 + k] = v3[(t * 50 + bi) * 16 + k];
  }
}

// ---------------- decoder ----------------
__global__ __launch_bounds__(512) void d1_k(const float* __restrict__ selv,
                                            const int* __restrict__ idxs,
                                            const float* __restrict__ d1w,
                                            const float* __restrict__ d1b,
                                            float* __restrict__ r1) {
  const int b = blockIdx.x, j = threadIdx.x;
  const int idx = idxs[b];
  const float* wr = d1w + j * 800 + idx * 16;
  float acc = d1b[j];
#pragma unroll
  for (int k = 0; k < 16; ++k) acc = fmaf(selv[b * 16 + k], wr[k], acc);
  r1[b * 512 + j] = acc > 0.f ? acc : 0.f;
}

__global__ __launch_bounds__(256) void d2_k(const float* __restrict__ r1,
                                            const float* __restrict__ d2w,
                                            const float* __restrict__ d2b,
                                            float* __restrict__ r2) {
  __shared__ float rl[512];
  const int b = blockIdx.y;
  const int j = blockIdx.x * 256 + threadIdx.x;
  for (int r = threadIdx.x; r < 512; r += 256) rl[r] = r1[b * 512 + r];
  __syncthreads();
  const float4* wr = (const float4*)(d2w + (long)j * 512);
  float acc = d2b[j];
  for (int k4 = 0; k4 < 128; ++k4) {
    const float4 w = wr[k4];
    acc += w.x * rl[k4 * 4] + w.y * rl[k4 * 4 + 1] + w.z * rl[k4 * 4 + 2] + w.w * rl[k4 * 4 + 3];
  }
  r2[b * 1024 + j] = acc > 0.f ? acc : 0.f;
}

__global__ __launch_bounds__(256) void d3_k(const float* __restrict__ r2,
                                            const float* __restrict__ d3w,
                                            const float* __restrict__ d3b,
                                            float* __restrict__ out) {
  __shared__ float rl[8192];
  const int j = blockIdx.x * 256 + threadIdx.x;
  float4* rl4 = (float4*)rl;
  for (int r = threadIdx.x; r < 2048; r += 256) rl4[r] = ((const float4*)r2)[r];
  __syncthreads();
  float acc[8];
  const float bv = d3b[j];
#pragma unroll
  for (int b = 0; b < 8; ++b) acc[b] = bv;
  const float4* wr = (const float4*)d3w + (long)j * 256;
  for (int k4 = 0; k4 < 256; ++k4) {
    const float4 w = wr[k4];
#pragma unroll
    for (int b = 0; b < 8; ++b) {
      const int o = b * 1024 + k4 * 4;
      acc[b] += w.x * rl[o] + w.y * rl[o + 1] + w.z * rl[o + 2] + w.w * rl[o + 3];
    }
  }
#pragma unroll
  for (int b = 0; b < 8; ++b)
    out[400 + b * 12288 + j] = 1.f / (1.f + __expf(-acc[b]));
}

extern "C" void kernel_launch(void* const* d_in, const int* in_sizes, int n_in,
                              void* d_out, int out_size, void* d_ws, size_t ws_size,
                              hipStream_t stream) {
  const float* x   = (const float*)d_in[0];
  const float* c1w = (const float*)d_in[1];
  const float* c1b = (const float*)d_in[2];
  const float* pw  = (const float*)d_in[3];
  const float* pb  = (const float*)d_in[4];
  const float* W   = (const float*)d_in[5];
  const float* d1w = (const float*)d_in[6];
  const float* d1b = (const float*)d_in[7];
  const float* d2w = (const float*)d_in[8];
  const float* d2b = (const float*)d_in[9];
  const float* d3w = (const float*)d_in[10];
  const float* d3b = (const float*)d_in[11];
  float* out = (float*)d_out;

  char* wsb = (char*)d_ws;
  size_t off = 0;
  auto alloc = [&](size_t bytes) -> char* {
    char* p = wsb + off;
    off += (bytes + 255) & ~(size_t)255;
    return p;
  };
  unsigned short* h_bf   = (unsigned short*)alloc(12845056);  // bf16 h
  unsigned short* wbf    = (unsigned short*)alloc(10616832);  // bf16 tiled prim_w
  unsigned*       offt   = (unsigned*)alloc(82944);
  // C_part (18.9 MB) and S_part (14.75 MB) alias (disjoint lifetimes).
  char*           bigA   = alloc(18874368);
  float*          C_part = (float*)bigA;
  float*          S_part = (float*)bigA;
  float*          u      = (float*)alloc(4718592);
  uint4*          u_h    = (uint4*)alloc(2359296);   // f16 u
  float*          vsum   = (float*)alloc(25600);
  float*          v3     = (float*)alloc(25600);
  float*          selv   = (float*)alloc(512);
  int*            idxs   = (int*)alloc(64);
  float*          r1     = (float*)alloc(16384);
  float*          r2     = (float*)alloc(32768);
  const size_t off_base = off;
  uint4*          Whf    = (uint4*)alloc(235929600);  // f16 routing W
  const bool f16_route = (off <= ws_size);
  if (off_base > ws_size) return;  // even fallback doesn't fit: outputs stay poisoned

  offtab_k<<<81, 256, 0, stream>>>(offt);
  wconv_k<<<2592, 256, 0, stream>>>(pw, wbf);
  conv1_k<<<2048, 256, 0, stream>>>(x, c1w, c1b, h_bf);
  prim_gemm<<<dim3(72, 4), 512, 0, stream>>>(h_bf, (const uint4*)wbf, offt, C_part);
  combine_k<<<576, 256, 0, stream>>>(C_part, pb, u, u_h);
  if (f16_route) wcvt_k<<<28800, 512, 0, stream>>>(W, Whf);
  hipMemsetAsync(vsum, 0, 25600, stream);
  for (int pass = 1; pass <= 3; ++pass) {
    if (f16_route)
      route_f16<<<576, 256, 0, stream>>>(Whf, u_h, vsum, S_part);
    else
      route_pass_f32<<<576, 512, 0, stream>>>(W, u, vsum, S_part);
    route_reduce<<<400, 256, 0, stream>>>(S_part, vsum, v3, pass);
  }
  head_k<<<1, 512, 0, stream>>>(v3, out, selv, idxs);
  d1_k<<<8, 512, 0, stream>>>(selv, idxs, d1w, d1b, r1);
  d2_k<<<dim3(4, 8), 256, 0, stream>>>(r1, d2w, d2b, r2);
  d3_k<<<48, 256, 0, stream>>>(r2, d3w, d3b, out);
}

// Round 6
// 705.113 us; speedup vs baseline: 4.2667x; 1.0852x over previous
//
#include <hip/hip_runtime.h>

typedef short short8 __attribute__((ext_vector_type(8)));
typedef float f32x4 __attribute__((ext_vector_type(4)));
typedef _Float16 h2 __attribute__((ext_vector_type(2)));

__device__ __forceinline__ unsigned short f2bf(float f) {
  union { float f; unsigned u; } a; a.f = f;
  unsigned r = a.u + 0x7fffu + ((a.u >> 16) & 1u);
  return (unsigned short)(r >> 16);
}

__device__ __forceinline__ h2 u2h2(unsigned w) {
  union { unsigned u; h2 h; } q; q.u = w; return q.h;
}

#if __has_builtin(__builtin_amdgcn_fdot2)
#define FDOT2(a, b, c) __builtin_amdgcn_fdot2((a), (b), (c), false)
#else
#define FDOT2(a, b, c) ((c) + (float)(a)[0] * (float)(b)[0] + (float)(a)[1] * (float)(b)[1])
#endif

// ---------------- tap offset table: off[k] = ci*3136 + ky*56 + kx ----------------
__global__ void offtab_k(unsigned* __restrict__ off_tab) {
  const int k = blockIdx.x * 256 + threadIdx.x;  // 81*256 = 20736 exact
  const int ci = k / 81, rr = k % 81;
  const int ky = rr / 9, kx = rr % 9;
  off_tab[k] = (unsigned)(ci * 3136 + ky * 56 + kx);
}

// ---------------- prim_w fp32 -> bf16 tiled [kb][co][8] ----------------
__global__ __launch_bounds__(256) void wconv_k(const float* __restrict__ pw,
                                               unsigned short* __restrict__ wbf) {
  const int kb = blockIdx.x, co = threadIdx.x;  // 2592 blocks
  const float4* src = (const float4*)(pw + (long)co * 20736 + kb * 8);
  const float4 a = src[0], b = src[1];
  union { unsigned short s[8]; short8 v; } o;
  o.s[0] = f2bf(a.x); o.s[1] = f2bf(a.y); o.s[2] = f2bf(a.z); o.s[3] = f2bf(a.w);
  o.s[4] = f2bf(b.x); o.s[5] = f2bf(b.y); o.s[6] = f2bf(b.z); o.s[7] = f2bf(b.w);
  *reinterpret_cast<short8*>(&wbf[((long)kb * 256 + co) * 8]) = o.v;
}

// ---------------- conv1: [8,3,64,64] -> bf16 h [8,256,56,56], relu ----------------
__global__ __launch_bounds__(256) void conv1_k(const float* __restrict__ x,
                                               const float* __restrict__ w,
                                               const float* __restrict__ bias,
                                               unsigned short* __restrict__ h_bf) {
  __shared__ float xl[12288];
  __shared__ float wl[244];
  const int blk = blockIdx.x;          // 2048 = 8b * 256co
  const int b = blk >> 8, co = blk & 255;
  const int t = threadIdx.x;
  const float4* xb = (const float4*)(x + b * 12288);
  float4* xl4 = (float4*)xl;
  for (int r = t; r < 3072; r += 256) xl4[r] = xb[r];
  for (int r = t; r < 243; r += 256) wl[r] = w[co * 243 + r];
  __syncthreads();
  if (t >= 224) return;
  const int ox = t % 56, oy0 = (t / 56) * 14;
  float acc[14];
#pragma unroll
  for (int j = 0; j < 14; ++j) acc[j] = 0.f;
  for (int ci = 0; ci < 3; ++ci)
    for (int kx = 0; kx < 9; ++kx) {
      const int base = ci * 4096 + oy0 * 64 + ox + kx;
      float win[22];
#pragma unroll
      for (int q = 0; q < 22; ++q) win[q] = xl[base + q * 64];
#pragma unroll
      for (int ky = 0; ky < 9; ++ky) {
        const float wv = wl[ci * 81 + ky * 9 + kx];
#pragma unroll
        for (int j = 0; j < 14; ++j) acc[j] = fmaf(wv, win[j + ky], acc[j]);
      }
    }
  const float bv = bias[co];
  unsigned short* hp = h_bf + (((long)b * 256 + co) * 56 + oy0) * 56 + ox;
#pragma unroll
  for (int j = 0; j < 14; ++j) {
    float v = acc[j] + bv;
    v = v > 0.f ? v : 0.f;
    hp[j * 56] = f2bf(v);
  }
}

// ---------------- prim conv implicit GEMM v2 ----------------
// C[m=4608][co=256], K=20736. grid (72 mtile, 4 ksplit), 512 thr = 8 waves (2M x 4N).
__global__ __launch_bounds__(512) void prim_gemm(const unsigned short* __restrict__ h_bf,
                                                 const uint4* __restrict__ wbf4,
                                                 const unsigned* __restrict__ off_tab,
                                                 float* __restrict__ C_part) {
  __shared__ uint4 A4[256];    // [c:4][row:64]
  __shared__ uint4 B4[1024];   // [c:4][co:256]
  const int t = threadIdx.x;
  const int lane = t & 63, w = t >> 6;
  const int mt = blockIdx.x, kz = blockIdx.y;
  const int k0 = kz * 5184;  // 162 k-steps of 32
  const bool isA = (t < 256);
  const int ar = t & 63, ac = (t >> 6) & 3;
  const int m = mt * 64 + ar;
  const int b = m / 576, yx = m % 576;
  const int oy = yx / 24, ox = yx % 24;
  const long base_p = (long)b * 802816 + oy * 112 + ox * 2;
  const int bco = t & 255;
  const int wm = w >> 2, wn = w & 3;
  const int fr = lane & 15, fg = lane >> 4;
  f32x4 acc[2][4];
#pragma unroll
  for (int i2 = 0; i2 < 2; ++i2)
#pragma unroll
    for (int j = 0; j < 4; ++j)
#pragma unroll
      for (int e = 0; e < 4; ++e) acc[i2][j][e] = 0.f;

  union { unsigned short s[8]; uint4 v; } pa;
  uint4 pb0, pb1, pb2, pb3;
  auto loadA = [&](int kt) {
    const int kb = k0 + kt * 32 + ac * 8;
#pragma unroll
    for (int j = 0; j < 8; ++j) pa.s[j] = h_bf[base_p + off_tab[kb + j]];
  };
  auto loadB = [&](int kt) {
    const int kb0 = (k0 + kt * 32) >> 3;
    pb0 = wbf4[(kb0 + 0) * 256 + bco];
    pb1 = wbf4[(kb0 + 1) * 256 + bco];
    pb2 = wbf4[(kb0 + 2) * 256 + bco];
    pb3 = wbf4[(kb0 + 3) * 256 + bco];
  };
  if (isA) loadA(0); else loadB(0);

  const short8* A8 = (const short8*)A4;
  const short8* B8 = (const short8*)B4;
  for (int kt = 0; kt < 162; ++kt) {
    __syncthreads();
    if (isA) {
      A4[ac * 64 + ar] = pa.v;
    } else {
      B4[bco] = pb0;
      B4[256 + bco] = pb1;
      B4[512 + bco] = pb2;
      B4[768 + bco] = pb3;
    }
    if (kt < 161) { if (isA) loadA(kt + 1); else loadB(kt + 1); }
    __syncthreads();
    const short8 a0 = A8[fg * 64 + wm * 32 + fr];
    const short8 a1 = A8[fg * 64 + wm * 32 + 16 + fr];
    const short8 b0 = B8[fg * 256 + wn * 64 + fr];
    const short8 b1 = B8[fg * 256 + wn * 64 + 16 + fr];
    const short8 b2 = B8[fg * 256 + wn * 64 + 32 + fr];
    const short8 b3 = B8[fg * 256 + wn * 64 + 48 + fr];
    acc[0][0] = __builtin_amdgcn_mfma_f32_16x16x32_bf16(a0, b0, acc[0][0], 0, 0, 0);
    acc[0][1] = __builtin_amdgcn_mfma_f32_16x16x32_bf16(a0, b1, acc[0][1], 0, 0, 0);
    acc[0][2] = __builtin_amdgcn_mfma_f32_16x16x32_bf16(a0, b2, acc[0][2], 0, 0, 0);
    acc[0][3] = __builtin_amdgcn_mfma_f32_16x16x32_bf16(a0, b3, acc[0][3], 0, 0, 0);
    acc[1][0] = __builtin_amdgcn_mfma_f32_16x16x32_bf16(a1, b0, acc[1][0], 0, 0, 0);
    acc[1][1] = __builtin_amdgcn_mfma_f32_16x16x32_bf16(a1, b1, acc[1][1], 0, 0, 0);
    acc[1][2] = __builtin_amdgcn_mfma_f32_16x16x32_bf16(a1, b2, acc[1][2], 0, 0, 0);
    acc[1][3] = __builtin_amdgcn_mfma_f32_16x16x32_bf16(a1, b3, acc[1][3], 0, 0, 0);
  }
#pragma unroll
  for (int i2 = 0; i2 < 2; ++i2)
#pragma unroll
    for (int j = 0; j < 4; ++j)
#pragma unroll
      for (int e = 0; e < 4; ++e) {
        const int row = mt * 64 + wm * 32 + i2 * 16 + fg * 4 + e;
        const int col = wn * 64 + j * 16 + fr;
        C_part[((long)kz * 4608 + row) * 256 + col] = acc[i2][j][e];
      }
}

// ------- combine K-split partials + bias + squash -> u fp32 + u_h f16 [8,18432,8] -------
__global__ __launch_bounds__(256) void combine_k(const float* __restrict__ C_part,
                                                 const float* __restrict__ prim_b,
                                                 float* __restrict__ u,
                                                 uint4* __restrict__ u_h) {
  const int cap = blockIdx.x * 256 + threadIdx.x;
  const int b = cap / 18432, r = cap % 18432;
  const int g = r / 576, yx = r % 576;
  const long m = (long)b * 576 + yx;
  float pv[8];
#pragma unroll
  for (int e = 0; e < 8; ++e) pv[e] = prim_b[g * 8 + e];
#pragma unroll
  for (int kz = 0; kz < 4; ++kz) {
    const float4* cp = (const float4*)(C_part + ((long)kz * 4608 + m) * 256 + g * 8);
    const float4 f0 = cp[0], f1 = cp[1];
    pv[0] += f0.x; pv[1] += f0.y; pv[2] += f0.z; pv[3] += f0.w;
    pv[4] += f1.x; pv[5] += f1.y; pv[6] += f1.z; pv[7] += f1.w;
  }
  float sn = 0.f;
#pragma unroll
  for (int e = 0; e < 8; ++e) sn += pv[e] * pv[e];
  const float f = sn / (1.f + sn) / (sqrtf(sn) + 1e-8f);
  float4 o0, o1;
  o0.x = pv[0] * f; o0.y = pv[1] * f; o0.z = pv[2] * f; o0.w = pv[3] * f;
  o1.x = pv[4] * f; o1.y = pv[5] * f; o1.z = pv[6] * f; o1.w = pv[7] * f;
  float4* up = (float4*)(u + (long)cap * 8);
  up[0] = o0; up[1] = o1;
  union { _Float16 h[8]; uint4 v; } oh;
  oh.h[0] = (_Float16)o0.x; oh.h[1] = (_Float16)o0.y; oh.h[2] = (_Float16)o0.z; oh.h[3] = (_Float16)o0.w;
  oh.h[4] = (_Float16)o1.x; oh.h[5] = (_Float16)o1.y; oh.h[6] = (_Float16)o1.z; oh.h[7] = (_Float16)o1.w;
  u_h[cap] = oh.v;
}

// ---------------- fused pass1 + W conversion ----------------
// Pass 1's softmax is exactly uniform (b_log=0 -> sc=1/50), so S1 = sum_i u_hat
// (scaled by 0.02 in the reducer). 28800 blocks x 512 thr; block = (n, 32 i).
// Thread = one W unit [n][i][d][e0..7] fp32: converts+stores f16 (side effect for
// passes 2/3) and dots against u[b,i,:] (LDS-staged) for all 8 b; block-reduces
// over its 32 i -> S1[blk][b*16+d].
__global__ __launch_bounds__(512) void route1_fused(const float* __restrict__ W,
                                                    const float* __restrict__ u,
                                                    uint4* __restrict__ Wh,
                                                    float* __restrict__ S1) {
  __shared__ float4 u_l[8][64];   // [b][i_local*2+half] = u[b][i0+i_local][4 elems]
  __shared__ float red[8][128];
  const int blk = blockIdx.x;
  const int t = threadIdx.x;
  const int i0 = (blk % 576) * 32;
  const long unit = (long)blk * 512 + t;
  {
    const int b = t >> 6, f = t & 63;
    u_l[b][f] = ((const float4*)(u + ((long)b * 18432 + i0) * 8))[f];
  }
  const float4* ws = (const float4*)(W + unit * 8);
  const float4 wa = ws[0], wb = ws[1];
  union { _Float16 h[8]; uint4 v; } o;
  o.h[0] = (_Float16)wa.x; o.h[1] = (_Float16)wa.y; o.h[2] = (_Float16)wa.z; o.h[3] = (_Float16)wa.w;
  o.h[4] = (_Float16)wb.x; o.h[5] = (_Float16)wb.y; o.h[6] = (_Float16)wb.z; o.h[7] = (_Float16)wb.w;
  Wh[unit] = o.v;
  __syncthreads();
  const int il = t >> 4;           // i_local 0..31
  const int w = t >> 6, lane = t & 63;
  float uh[8];
#pragma unroll
  for (int b = 0; b < 8; ++b) {
    const float4 p0 = u_l[b][il * 2], p1 = u_l[b][il * 2 + 1];
    uh[b] = wa.x * p0.x + wa.y * p0.y + wa.z * p0.z + wa.w * p0.w +
            wb.x * p1.x + wb.y * p1.y + wb.z * p1.z + wb.w * p1.w;
  }
#pragma unroll
  for (int b = 0; b < 8; ++b) {
    float v = uh[b];
    v += __shfl_xor(v, 16);   // reduce over i_local bits 0,1 (lane bits 4,5)
    v += __shfl_xor(v, 32);
    if (lane < 16) red[w][b * 16 + lane] = v;  // lane == d here
  }
  __syncthreads();
  if (t < 128) {
    float s = 0.f;
#pragma unroll
    for (int w2 = 0; w2 < 8; ++w2) s += red[w2][t];
    S1[(long)blk * 128 + t] = s;
  }
}

// ---------------- reduce pass1 partials: 576 per n; x0.02 then squash -> vsum ----
__global__ __launch_bounds__(256) void route_reduce1(const float* __restrict__ S1,
                                                     float* __restrict__ vsum) {
  __shared__ float lds[256];
  const int bn = blockIdx.x;  // 400 = b*50+n
  const int b = bn / 50, n = bn % 50;
  const int t = threadIdx.x;
  const int kk = t >> 4, dd = t & 15;
  float s = 0.f;
  const float* p = S1 + (long)n * 576 * 128 + b * 16 + dd;
  for (int j = kk; j < 576; j += 16) s += p[(long)j * 128];
  lds[t] = s;
  __syncthreads();
  for (int off = 128; off >= 16; off >>= 1) {
    if (t < off) lds[t] += lds[t + off];
    __syncthreads();
  }
  if (t < 16) {
    const float S = lds[t] * 0.02f;   // sc = 1/50, applied BEFORE squash
    float sq = S * S;
    sq += __shfl_xor(sq, 1);
    sq += __shfl_xor(sq, 2);
    sq += __shfl_xor(sq, 4);
    sq += __shfl_xor(sq, 8);
    const float f = sq / (1.f + sq) / (sqrtf(sq) + 1e-8f);
    vsum[bn * 16 + t] += S * f;       // vsum was zeroed
  }
}

// ---------------- routing passes 2/3: f16 W + fdot2, lane = class, 2 batches/wave ----
// 1152 blocks x 256 thr (4 waves). wave w -> b = {2w, 2w+1}; lane = n. Block owns 16 i
// (8 chunks of 2 i). W staged via LDS (XOR-swizzled 16B slots), 1-chunk reg prefetch.
__global__ __launch_bounds__(256) void route_f16(const uint4* __restrict__ Wb4,
                                                 const uint4* __restrict__ u_h,
                                                 const float* __restrict__ vsum,
                                                 float* __restrict__ S_part) {
  __shared__ uint4 lds4[1600];
  const int t = threadIdx.x;
  const int w = t >> 6, lane = t & 63;
  const int b0 = 2 * w, b1 = 2 * w + 1;
  const bool vn = lane < 50;
  const int nr = vn ? lane : 49;
  const int nxor = nr & 15;
  const int bi = blockIdx.x;
  const int i_base = bi * 16;

  float vs0[16], vs1[16], Sa0[16], Sa1[16];
#pragma unroll
  for (int d = 0; d < 16; ++d) {
    vs0[d] = vsum[(b0 * 50 + nr) * 16 + d];
    vs1[d] = vsum[(b1 * 50 + nr) * 16 + d];
    Sa0[d] = 0.f;
    Sa1[d] = 0.f;
  }

  auto gload = [&](int idx, int i0) -> uint4 {
    const int n = idx >> 5, i2 = (idx >> 4) & 1, c = idx & 15;
    return Wb4[(long)(n * 18432 + i0 + i2) * 16 + c];
  };
  auto lput = [&](int idx, uint4 v) {
    const int n = idx >> 5, i2 = (idx >> 4) & 1, c = idx & 15;
    lds4[n * 32 + i2 * 16 + (c ^ (n & 15))] = v;
  };
  const bool g6 = t < 64;
  uint4 r[7];
  const uint4 zz = make_uint4(0, 0, 0, 0);
#pragma unroll
  for (int k = 0; k < 6; ++k) r[k] = gload(t + 256 * k, i_base);
  r[6] = g6 ? gload(t + 1536, i_base) : zz;

  for (int ch = 0; ch < 8; ++ch) {
    __syncthreads();
#pragma unroll
    for (int k = 0; k < 6; ++k) lput(t + 256 * k, r[k]);
    if (g6) lput(t + 1536, r[6]);
    if (ch < 7) {
      const int ni = i_base + (ch + 1) * 2;
#pragma unroll
      for (int k = 0; k < 6; ++k) r[k] = gload(t + 256 * k, ni);
      if (g6) r[6] = gload(t + 1536, ni);
    }
    __syncthreads();
#pragma unroll
    for (int ii = 0; ii < 2; ++ii) {
      const int i = i_base + ch * 2 + ii;
      const uint4 uv0 = u_h[(long)b0 * 18432 + i];
      const uint4 uv1 = u_h[(long)b1 * 18432 + i];
      const h2 a00 = u2h2(uv0.x), a01 = u2h2(uv0.y), a02 = u2h2(uv0.z), a03 = u2h2(uv0.w);
      const h2 a10 = u2h2(uv1.x), a11 = u2h2(uv1.y), a12 = u2h2(uv1.z), a13 = u2h2(uv1.w);
      const uint4* lrow = &lds4[nr * 32 + ii * 16];
      float uh0[16], uh1[16];
      float lg0 = 0.f, lg1 = 0.f;
#pragma unroll
      for (int d = 0; d < 16; ++d) {
        const uint4 wv = lrow[d ^ nxor];
        const h2 w0 = u2h2(wv.x), w1 = u2h2(wv.y), w2 = u2h2(wv.z), w3 = u2h2(wv.w);
        float s0 = FDOT2(w0, a00, 0.f);
        s0 = FDOT2(w1, a01, s0);
        s0 = FDOT2(w2, a02, s0);
        s0 = FDOT2(w3, a03, s0);
        uh0[d] = s0;
        lg0 = fmaf(s0, vs0[d], lg0);
        float s1 = FDOT2(w0, a10, 0.f);
        s1 = FDOT2(w1, a11, s1);
        s1 = FDOT2(w2, a12, s1);
        s1 = FDOT2(w3, a13, s1);
        uh1[d] = s1;
        lg1 = fmaf(s1, vs1[d], lg1);
      }
      float p0 = vn ? __expf(lg0) : 0.f;
      float p1 = vn ? __expf(lg1) : 0.f;
      float sm0 = p0, sm1 = p1;
      sm0 += __shfl_xor(sm0, 1);
      sm1 += __shfl_xor(sm1, 1);
      sm0 += __shfl_xor(sm0, 2);
      sm1 += __shfl_xor(sm1, 2);
      sm0 += __shfl_xor(sm0, 4);
      sm1 += __shfl_xor(sm1, 4);
      sm0 += __shfl_xor(sm0, 8);
      sm1 += __shfl_xor(sm1, 8);
      sm0 += __shfl_xor(sm0, 16);
      sm1 += __shfl_xor(sm1, 16);
      sm0 += __shfl_xor(sm0, 32);
      sm1 += __shfl_xor(sm1, 32);
      const float sc0 = p0 / sm0;
      const float sc1 = p1 / sm1;
#pragma unroll
      for (int d = 0; d < 16; ++d) {
        Sa0[d] = fmaf(sc0, uh0[d], Sa0[d]);
        Sa1[d] = fmaf(sc1, uh1[d], Sa1[d]);
      }
    }
  }
  if (vn) {
    float* Sp0 = S_part + (long)bi * 6400 + b0 * 800 + lane * 16;
    float* Sp1 = S_part + (long)bi * 6400 + b1 * 800 + lane * 16;
#pragma unroll
    for (int d = 0; d < 16; ++d) {
      Sp0[d] = Sa0[d];
      Sp1[d] = Sa1[d];
    }
  }
}

// ---------------- routing pass (fp32 fallback, proven; 576 blocks) ----------------
__global__ __launch_bounds__(512, 4) void route_pass_f32(const float* __restrict__ W,
                                                         const float* __restrict__ u,
                                                         const float* __restrict__ vsum,
                                                         float* __restrict__ S_part) {
  const int t = threadIdx.x;
  const int b = t >> 6;
  const int lane = t & 63;
  const int d = lane & 15, nq = lane >> 4;
  const int qmax = (nq == 3) ? 11 : 13;
  int nn[13];
  float vs[13], Sa[13], uh[13], lg[13];
#pragma unroll
  for (int q = 0; q < 13; ++q) {
    const int n = nq * 13 + q;
    const bool valid = n < 50;
    nn[q] = valid ? n : 49;
    vs[q] = valid ? vsum[(b * 50 + n) * 16 + d] : 0.f;
    Sa[q] = 0.f;
  }
  const int bi = blockIdx.x;
  for (int ii = 0; ii < 32; ++ii) {
    const int i = bi * 32 + ii;
    const float4* up = (const float4*)(u + ((long)b * 18432 + i) * 8);
    const float4 u0 = up[0], u1 = up[1];
    const float* Wi = W + (long)i * 128 + d * 8;
#pragma unroll
    for (int q = 0; q < 13; ++q) {
      const float4* wp = (const float4*)(Wi + (long)nn[q] * 2359296);
      const float4 w0 = wp[0], w1 = wp[1];
      const float s = w0.x * u0.x + w0.y * u0.y + w0.z * u0.z + w0.w * u0.w +
                      w1.x * u1.x + w1.y * u1.y + w1.z * u1.z + w1.w * u1.w;
      uh[q] = s;
      float v = s * vs[q];
      v += __shfl_xor(v, 1);
      v += __shfl_xor(v, 2);
      v += __shfl_xor(v, 4);
      v += __shfl_xor(v, 8);
      lg[q] = (q < qmax) ? v : -1e30f;
    }
    float mx = lg[0];
#pragma unroll
    for (int q = 1; q < 13; ++q) mx = fmaxf(mx, lg[q]);
    mx = fmaxf(mx, __shfl_xor(mx, 16));
    mx = fmaxf(mx, __shfl_xor(mx, 32));
    float sm = 0.f;
#pragma unroll
    for (int q = 0; q < 13; ++q) {
      const float e = __expf(lg[q] - mx);
      lg[q] = e;
      sm += e;
    }
    sm += __shfl_xor(sm, 16);
    sm += __shfl_xor(sm, 32);
    const float inv = 1.f / sm;
#pragma unroll
    for (int q = 0; q < 13; ++q) Sa[q] = fmaf(lg[q] * inv, uh[q], Sa[q]);
  }
  float* Sp = S_part + ((long)bi * 8 + b) * 800;
#pragma unroll
  for (int q = 0; q < 13; ++q)
    if (q < qmax) Sp[(nq * 13 + q) * 16 + d] = Sa[q];
}

// ---------------- reduce nparts partials -> v = squash(S); vsum += v or v3 = v ------
__global__ __launch_bounds__(256) void route_reduce(const float* __restrict__ S_part,
                                                    float* __restrict__ vsum,
                                                    float* __restrict__ v3,
                                                    const int pass, const int nparts) {
  __shared__ float lds[256];
  const int bn = blockIdx.x;  // 400 = b*50+n
  const int b = bn / 50, n = bn % 50;
  const int t = threadIdx.x;
  const int kk = t >> 4, dd = t & 15;
  float s = 0.f;
  const float* p = S_part + (long)b * 800 + n * 16 + dd;
  for (int j = kk; j < nparts; j += 16) s += p[(long)j * 6400];
  lds[t] = s;
  __syncthreads();
  for (int off = 128; off >= 16; off >>= 1) {
    if (t < off) lds[t] += lds[t + off];
    __syncthreads();
  }
  if (t < 16) {
    const float S = lds[t];
    float sq = S * S;
    sq += __shfl_xor(sq, 1);
    sq += __shfl_xor(sq, 2);
    sq += __shfl_xor(sq, 4);
    sq += __shfl_xor(sq, 8);
    const float f = sq / (1.f + sq) / (sqrtf(sq) + 1e-8f);
    const float v = S * f;
    const int o = bn * 16 + t;
    if (pass < 3) vsum[o] += v;
    else v3[o] = v;
  }
}

// ---------------- preds, argmax, select masked capsule ----------------
__global__ __launch_bounds__(512) void head_k(const float* __restrict__ v3,
                                              float* __restrict__ out,
                                              float* __restrict__ selv,
                                              int* __restrict__ idxs) {
  __shared__ float pl[400];
  const int t = threadIdx.x;
  if (t < 400) {
    const float4* vp = (const float4*)(v3 + t * 16);
    const float4 a = vp[0], b = vp[1], c = vp[2], d = vp[3];
    const float s = a.x * a.x + a.y * a.y + a.z * a.z + a.w * a.w +
                    b.x * b.x + b.y * b.y + b.z * b.z + b.w * b.w +
                    c.x * c.x + c.y * c.y + c.z * c.z + c.w * c.w +
                    d.x * d.x + d.y * d.y + d.z * d.z + d.w * d.w;
    const float p = sqrtf(s);
    out[t] = p;
    pl[t] = p;
  }
  __syncthreads();
  if (t < 8) {
    float best = -1e30f;
    int bi = 0;
    for (int n = 0; n < 50; ++n) {
      const float p = pl[t * 50 + n];
      if (p > best) { best = p; bi = n; }
    }
    idxs[t] = bi;
    for (int k = 0; k < 16; ++k) selv[t * 16 + k] = v3[(t * 50 + bi) * 16 + k];
  }
}

// ---------------- decoder ----------------
__global__ __launch_bounds__(512) void d1_k(const float* __restrict__ selv,
                                            const int* __restrict__ idxs,
                                            const float* __restrict__ d1w,
                                            const float* __restrict__ d1b,
                                            float* __restrict__ r1) {
  const int b = blockIdx.x, j = threadIdx.x;
  const int idx = idxs[b];
  const float* wr = d1w + j * 800 + idx * 16;
  float acc = d1b[j];
#pragma unroll
  for (int k = 0; k < 16; ++k) acc = fmaf(selv[b * 16 + k], wr[k], acc);
  r1[b * 512 + j] = acc > 0.f ? acc : 0.f;
}

__global__ __launch_bounds__(256) void d2_k(const float* __restrict__ r1,
                                            const float* __restrict__ d2w,
                                            const float* __restrict__ d2b,
                                            float* __restrict__ r2) {
  __shared__ float rl[512];
  const int b = blockIdx.y;
  const int j = blockIdx.x * 256 + threadIdx.x;
  for (int r = threadIdx.x; r < 512; r += 256) rl[r] = r1[b * 512 + r];
  __syncthreads();
  const float4* wr = (const float4*)(d2w + (long)j * 512);
  float acc = d2b[j];
  for (int k4 = 0; k4 < 128; ++k4) {
    const float4 w = wr[k4];
    acc += w.x * rl[k4 * 4] + w.y * rl[k4 * 4 + 1] + w.z * rl[k4 * 4 + 2] + w.w * rl[k4 * 4 + 3];
  }
  r2[b * 1024 + j] = acc > 0.f ? acc : 0.f;
}

__global__ __launch_bounds__(256) void d3_k(const float* __restrict__ r2,
                                            const float* __restrict__ d3w,
                                            const float* __restrict__ d3b,
                                            float* __restrict__ out) {
  __shared__ float rl[8192];
  const int j = blockIdx.x * 256 + threadIdx.x;
  float4* rl4 = (float4*)rl;
  for (int r = threadIdx.x; r < 2048; r += 256) rl4[r] = ((const float4*)r2)[r];
  __syncthreads();
  float acc[8];
  const float bv = d3b[j];
#pragma unroll
  for (int b = 0; b < 8; ++b) acc[b] = bv;
  const float4* wr = (const float4*)d3w + (long)j * 256;
  for (int k4 = 0; k4 < 256; ++k4) {
    const float4 w = wr[k4];
#pragma unroll
    for (int b = 0; b < 8; ++b) {
      const int o = b * 1024 + k4 * 4;
      acc[b] += w.x * rl[o] + w.y * rl[o + 1] + w.z * rl[o + 2] + w.w * rl[o + 3];
    }
  }
#pragma unroll
  for (int b = 0; b < 8; ++b)
    out[400 + b * 12288 + j] = 1.f / (1.f + __expf(-acc[b]));
}

extern "C" void kernel_launch(void* const* d_in, const int* in_sizes, int n_in,
                              void* d_out, int out_size, void* d_ws, size_t ws_size,
                              hipStream_t stream) {
  const float* x   = (const float*)d_in[0];
  const float* c1w = (const float*)d_in[1];
  const float* c1b = (const float*)d_in[2];
  const float* pw  = (const float*)d_in[3];
  const float* pb  = (const float*)d_in[4];
  const float* W   = (const float*)d_in[5];
  const float* d1w = (const float*)d_in[6];
  const float* d1b = (const float*)d_in[7];
  const float* d2w = (const float*)d_in[8];
  const float* d2b = (const float*)d_in[9];
  const float* d3w = (const float*)d_in[10];
  const float* d3b = (const float*)d_in[11];
  float* out = (float*)d_out;

  char* wsb = (char*)d_ws;
  size_t off = 0;
  auto alloc = [&](size_t bytes) -> char* {
    char* p = wsb + off;
    off += (bytes + 255) & ~(size_t)255;
    return p;
  };
  unsigned short* h_bf   = (unsigned short*)alloc(12845056);  // bf16 h
  unsigned short* wbf    = (unsigned short*)alloc(10616832);  // bf16 tiled prim_w
  unsigned*       offt   = (unsigned*)alloc(82944);
  // bigA aliases: C_part (18.9 MB) -> S1 (14.7 MB) -> S_part23 (29.5 MB); disjoint lifetimes.
  char*           bigA   = alloc(29491200);
  float*          C_part = (float*)bigA;
  float*          S1     = (float*)bigA;
  float*          S_part = (float*)bigA;
  float*          u      = (float*)alloc(4718592);
  uint4*          u_h    = (uint4*)alloc(2359296);   // f16 u
  float*          vsum   = (float*)alloc(25600);
  float*          v3     = (float*)alloc(25600);
  float*          selv   = (float*)alloc(512);
  int*            idxs   = (int*)alloc(64);
  float*          r1     = (float*)alloc(16384);
  float*          r2     = (float*)alloc(32768);
  const size_t off_base = off;
  uint4*          Whf    = (uint4*)alloc(235929600);  // f16 routing W
  const bool f16_route = (off <= ws_size);
  if (off_base > ws_size) return;  // even fallback doesn't fit: outputs stay poisoned

  offtab_k<<<81, 256, 0, stream>>>(offt);
  wconv_k<<<2592, 256, 0, stream>>>(pw, wbf);
  conv1_k<<<2048, 256, 0, stream>>>(x, c1w, c1b, h_bf);
  prim_gemm<<<dim3(72, 4), 512, 0, stream>>>(h_bf, (const uint4*)wbf, offt, C_part);
  combine_k<<<576, 256, 0, stream>>>(C_part, pb, u, u_h);
  hipMemsetAsync(vsum, 0, 25600, stream);
  if (f16_route) {
    // pass 1 fused with W fp32->f16 conversion (uniform softmax, exact)
    route1_fused<<<28800, 512, 0, stream>>>(W, u, Whf, S1);
    route_reduce1<<<400, 256, 0, stream>>>(S1, vsum);
    for (int pass = 2; pass <= 3; ++pass) {
      route_f16<<<1152, 256, 0, stream>>>(Whf, u_h, vsum, S_part);
      route_reduce<<<400, 256, 0, stream>>>(S_part, vsum, v3, pass, 1152);
    }
  } else {
    for (int pass = 1; pass <= 3; ++pass) {
      route_pass_f32<<<576, 512, 0, stream>>>(W, u, vsum, S_part);
      route_reduce<<<400, 256, 0, stream>>>(S_part, vsum, v3, pass, 576);
    }
  }
  head_k<<<1, 512, 0, stream>>>(v3, out, selv, idxs);
  d1_k<<<8, 512, 0, stream>>>(selv, idxs, d1w, d1b, r1);
  d2_k<<<dim3(4, 8), 256, 0, stream>>>(r1, d2w, d2b, r2);
  d3_k<<<48, 256, 0, stream>>>(r2, d3w, d3b, out);
}